// Round 1
// baseline (1953.311 us; speedup 1.0000x reference)
//
#include <hip/hip_runtime.h>
#include <hip/hip_bf16.h>
#include <stdint.h>

// STU forward: y = scan(m_y, (x_tilde @ m_phi) + AR(m_u, u))
// Restructured: conv and d-contraction commuted so both heavy stages are bf16 MFMA GEMMs.
// L=2048, D=768, K=24.

typedef unsigned short u16;
typedef unsigned int   u32;
typedef __bf16  bf16x8 __attribute__((ext_vector_type(8)));
typedef float   f32x4  __attribute__((ext_vector_type(4)));
typedef u32     u32x4  __attribute__((ext_vector_type(4)));

#define MFMA(a,b,c) __builtin_amdgcn_mfma_f32_16x16x32_bf16(a,b,c,0,0,0)

__device__ __forceinline__ u16 f2b(float f) {           // fp32 -> bf16 bits, RNE
  union { float f; u32 u; } v; v.f = f;
  return (u16)((v.u + 0x7fffu + ((v.u >> 16) & 1u)) >> 16);
}

// ---------------- workspace layout (bytes, all 256-aligned) ----------------
// ub     : [2050][768] bf16   u with 2 zero guard rows        @ 0
// mphiT  : [18432][768] bf16  scale_k * m_phi_k^T blocks      @ 3,148,800
// b2t    : [3][768][768] bf16 m_u[o][i][kk] -> [kk][o][i]     @ 31,460,352
// tt     : [16][24][128][128] bf16 Toeplitz tiles of eig_vecs @ 34,999,296
// zt     : [24][768][2048] bf16                                @ 47,582,208
// delta  : [2048][768] f32                                     @ 123,079,680
// stbuf  : [2][128][1536] bf16 (j interleaved: j=2i+h)         @ 129,371,136
// flags  : [2][8][64] int                                      @ 130,157,568
#define WS_UB     0
#define WS_MPHIT  3148800
#define WS_B2T    31460352
#define WS_TT     34999296
#define WS_ZT     47582208
#define WS_DELTA  123079680
#define WS_STBUF  129371136
#define WS_FLAGS  130157568

// ---------------------------------------------------------------------------
__global__ void k_zero(float* __restrict__ delta, int* __restrict__ flags) {
  int i = blockIdx.x * blockDim.x + threadIdx.x;
  int stride = gridDim.x * blockDim.x;
  for (int t = i; t < 2048 * 768; t += stride) delta[t] = 0.f;
  if (i < 1024) flags[i] = 0;
}

// u (fp32) -> bf16 with two zero guard rows in front (for AR shifted reads)
__global__ void k_repack_u(const float* __restrict__ u, u16* __restrict__ ub) {
  int i = blockIdx.x * blockDim.x + threadIdx.x;
  if (i >= 2050 * 768) return;
  ub[i] = (i < 2 * 768) ? (u16)0 : f2b(u[i - 2 * 768]);
}

// mphiT[(k*768+d')][d] = eig_vals[k]^0.25 * m_phi[(k*768+d)][d']   (per-k transpose)
__global__ void k_repack_mphi(const float* __restrict__ mphi, const float* __restrict__ ev,
                              u16* __restrict__ out) {
  __shared__ float tile[32][33];
  int bid = blockIdx.x;
  int k = bid / 576, rem = bid % 576;
  int ti = rem / 24, tj = rem % 24;        // ti: d-block, tj: d'-block
  int tid = threadIdx.x;
  int c = tid & 31, r0 = tid >> 5;         // 8 rows per pass
  float s = powf(ev[k], 0.25f);
  #pragma unroll
  for (int rr = 0; rr < 4; ++rr) {
    int r = r0 + (rr << 3);
    tile[r][c] = mphi[(k * 768 + ti * 32 + r) * 768 + tj * 32 + c];
  }
  __syncthreads();
  #pragma unroll
  for (int rr = 0; rr < 4; ++rr) {
    int r = r0 + (rr << 3);               // r = d'-local
    out[(k * 768 + tj * 32 + r) * 768 + ti * 32 + c] = f2b(tile[c][r] * s);
  }
}

// b2t[kk][o][i] = m_u[o][i][kk]
__global__ void k_repack_mu(const float* __restrict__ mu, u16* __restrict__ out) {
  int i = blockIdx.x * blockDim.x + threadIdx.x;
  if (i >= 3 * 768 * 768) return;
  int kk = i / (768 * 768);
  int rem = i % (768 * 768);
  int o = rem / 768, ii = rem % 768;
  out[i] = f2b(mu[(o * 768 + ii) * 3 + kk]);
}

// tt[dlt][k][r][c] = eig_vecs[128*dlt + r - c - 2][k]  (0 if OOB)
__global__ void k_make_T(const float* __restrict__ v, u16* __restrict__ out) {
  int i = blockIdx.x * blockDim.x + threadIdx.x;
  if (i >= 16 * 24 * 128 * 128) return;
  int c = i & 127, r = (i >> 7) & 127;
  int kk = (i >> 14) % 24, dlt = (i >> 14) / 24;
  int t = dlt * 128 + r - c - 2;
  out[i] = (t >= 0 && t < 2048) ? f2b(v[t * 24 + kk]) : (u16)0;
}

// ---------------------------------------------------------------------------
__device__ __forceinline__ void mfma_tile(const u16* As, const u16* Bs, int lane,
                                          int wm, int wn, f32x4 acc[4][4]) {
  #pragma unroll
  for (int ks = 0; ks < 2; ++ks) {
    int ko = ks * 32 + (lane >> 4) * 8;
    bf16x8 af[4], bg[4];
    #pragma unroll
    for (int i = 0; i < 4; ++i)
      af[i] = *(const bf16x8*)&As[(wm + i * 16 + (lane & 15)) * 64 + ko];
    #pragma unroll
    for (int j = 0; j < 4; ++j)
      bg[j] = *(const bf16x8*)&Bs[(wn + j * 16 + (lane & 15)) * 64 + ko];
    #pragma unroll
    for (int i = 0; i < 4; ++i)
      #pragma unroll
      for (int j = 0; j < 4; ++j)
        acc[i][j] = MFMA(af[i], bg[j], acc[i][j]);
  }
}

// K2: Zt[18432 x 2048] = mphiT[18432 x 768] @ ub[2048 x 768]^T (B stored [n][k])
__global__ __launch_bounds__(256) void k_gemm_zt(const u16* __restrict__ A,
                                                 const u16* __restrict__ B,
                                                 u16* __restrict__ C) {
  __shared__ __align__(16) u16 As[128 * 64];
  __shared__ __align__(16) u16 Bs[128 * 64];
  int bid = blockIdx.x;
  int nt = bid & 15, mt = bid >> 4;
  int m0 = mt << 7, n0 = nt << 7;
  int tid = threadIdx.x, lane = tid & 63, wave = tid >> 6;
  int wm = (wave & 1) << 6, wn = (wave >> 1) << 6;
  int trow = tid >> 3, tcol = (tid & 7) << 3;
  f32x4 acc[4][4] = {};
  for (int kb = 0; kb < 12; ++kb) {
    int k0 = kb << 6;
    #pragma unroll
    for (int rr = 0; rr < 4; ++rr) {
      int row = trow + (rr << 5);
      *(u32x4*)&As[row * 64 + tcol] = *(const u32x4*)&A[(m0 + row) * 768 + k0 + tcol];
      *(u32x4*)&Bs[row * 64 + tcol] = *(const u32x4*)&B[(n0 + row) * 768 + k0 + tcol];
    }
    __syncthreads();
    mfma_tile(As, Bs, lane, wm, wn, acc);
    __syncthreads();
  }
  int q = lane >> 4, cn = lane & 15;
  #pragma unroll
  for (int i = 0; i < 4; ++i)
    #pragma unroll
    for (int j = 0; j < 4; ++j)
      #pragma unroll
      for (int r = 0; r < 4; ++r) {
        int m = m0 + wm + i * 16 + q * 4 + r;
        int n = n0 + wn + j * 16 + cn;
        C[m * 2048 + n] = f2b(acc[i][j][r]);
      }
}

// K3: delta[l][d'] += sum_k T_k @ Zt[k]  + AR part. Split-K=4 over k, atomic f32 epilogue.
__global__ __launch_bounds__(256) void k_gemm_delta(const u16* __restrict__ tt,
                                                    const u16* __restrict__ zt,
                                                    const u16* __restrict__ ub,
                                                    const u16* __restrict__ b2t,
                                                    float* __restrict__ delta) {
  __shared__ __align__(16) u16 As[128 * 64];
  __shared__ __align__(16) u16 Bs[128 * 64];
  int bid = blockIdx.x;
  int sk = bid & 3;
  int r2 = bid >> 2;
  int db = r2 % 6;
  int lb = 15 - r2 / 6;                    // heavy tiles dispatched first
  int n0 = db << 7;
  int tid = threadIdx.x, lane = tid & 63, wave = tid >> 6;
  int wm = (wave & 1) << 6, wn = (wave >> 1) << 6;
  int trow = tid >> 3, tcol = (tid & 7) << 3;
  f32x4 acc[4][4] = {};
  // main causal-conv part: k in [6*sk, 6*sk+6), t'-blocks 0..lb, 64-wide halves
  for (int kk = sk * 6; kk < sk * 6 + 6; ++kk) {
    const u16* Bg = zt + kk * (768 * 2048);
    for (int th = 0; th < 2 * (lb + 1); ++th) {
      int tb = th >> 1, hf = th & 1;
      const u16* Ag = tt + ((lb - tb) * 24 + kk) * 16384;
      #pragma unroll
      for (int rr = 0; rr < 4; ++rr) {
        int row = trow + (rr << 5);
        *(u32x4*)&As[row * 64 + tcol] = *(const u32x4*)&Ag[row * 128 + hf * 64 + tcol];
        *(u32x4*)&Bs[row * 64 + tcol] =
            *(const u32x4*)&Bg[(n0 + row) * 2048 + tb * 128 + hf * 64 + tcol];
      }
      __syncthreads();
      mfma_tile(As, Bs, lane, wm, wn, acc);
      __syncthreads();
    }
  }
  // AR part on splits 0..2 (one kk tap each)
  if (sk < 3) {
    int kku = sk;
    const u16* Bg = b2t + kku * (768 * 768);
    for (int ic = 0; ic < 12; ++ic) {
      #pragma unroll
      for (int rr = 0; rr < 4; ++rr) {
        int row = trow + (rr << 5);
        *(u32x4*)&As[row * 64 + tcol] =
            *(const u32x4*)&ub[(2 + lb * 128 + row - kku) * 768 + ic * 64 + tcol];
        *(u32x4*)&Bs[row * 64 + tcol] =
            *(const u32x4*)&Bg[(n0 + row) * 768 + ic * 64 + tcol];
      }
      __syncthreads();
      mfma_tile(As, Bs, lane, wm, wn, acc);
      __syncthreads();
    }
  }
  int q = lane >> 4, cn = lane & 15;
  #pragma unroll
  for (int i = 0; i < 4; ++i)
    #pragma unroll
    for (int j = 0; j < 4; ++j)
      #pragma unroll
      for (int r = 0; r < 4; ++r) {
        int m = lb * 128 + wm + i * 16 + q * 4 + r;
        int n = n0 + wn + j * 16 + cn;
        unsafeAtomicAdd(&delta[m * 768 + n], acc[i][j][r]);
      }
}

// ---------------------------------------------------------------------------
// K4 scan: warm-up chunked linear recurrence.
// 128 chunks of C=16 rows, warm-up W=64 rows, 80 rounds.
// 8 groups x 48 WGs; WG holds W-slice [1536 x 16] in LDS (MFMA B-frag order).
// State j index interleaved: j=2i+h <-> (h? y_{t-2}: y_{t-1})[i]; one u32/word per (c,o).
__global__ __launch_bounds__(256, 2) void k_scan(const float* __restrict__ my,
                                                 const float* __restrict__ delta,
                                                 u16* __restrict__ stbuf,
                                                 int* __restrict__ flags,
                                                 float* __restrict__ out) {
  __shared__ __align__(16) u16 wblob[48 * 64 * 8];   // 49152 B
  __shared__ float red[4][16][16];                   // 4096 B
  int b = blockIdx.x;
  int g = b & 7, wgi = b >> 3;                       // 8 groups x 48 slices
  int tid = threadIdx.x, lane = tid & 63, wave = tid >> 6;
  int q = lane >> 4, cn = lane & 15;

  // load + swizzle weight slice: wblob[s][lane][jj] = W[j = s*32+q*8+jj][o = wgi*16+cn]
  {
    int o = wgi * 16 + cn;
    for (int s4 = 0; s4 < 48; s4 += 4) {
      int s = s4 + wave;
      short pk[8];
      #pragma unroll
      for (int jj = 0; jj < 8; ++jj) {
        int j = s * 32 + q * 8 + jj;
        pk[jj] = (short)f2b(my[o * 1536 + (j & 1) * 768 + (j >> 1)]);
      }
      *(bf16x8*)&wblob[(s * 64 + lane) * 8] = *(bf16x8*)pk;
    }
  }

  u32* st32 = (u32*)stbuf;  // [2][128][768] words
  // init state buffer 0 for this group's chunks / this WG's dims
  {
    int m = tid >> 4, col = tid & 15;
    int c = 16 * g + m, o = wgi * 16 + col;
    __hip_atomic_store(&st32[c * 768 + o], 0u, __ATOMIC_RELAXED, __HIP_MEMORY_SCOPE_AGENT);
  }

  // group sync helper (inlined per round): signal flag = n, wait for 48
  #define GROUP_SYNC(n)                                                                 \
    {                                                                                   \
      __builtin_amdgcn_s_waitcnt(0);                                                    \
      __syncthreads();                                                                  \
      int* slot = flags + (((n) & 1) << 9) + (g << 6);                                  \
      if (tid == 0)                                                                     \
        __hip_atomic_store(&slot[wgi], (n), __ATOMIC_RELAXED, __HIP_MEMORY_SCOPE_AGENT);\
      if (tid < 64) {                                                                   \
        while (1) {                                                                     \
          int v = (tid < 48) ? __hip_atomic_load(&slot[tid], __ATOMIC_RELAXED,          \
                                                 __HIP_MEMORY_SCOPE_AGENT)              \
                             : 0x7fffffff;                                              \
          if (__all(v >= (n))) break;                                                   \
          __builtin_amdgcn_s_sleep(8);                                                  \
        }                                                                               \
      }                                                                                 \
      __syncthreads();                                                                  \
      __builtin_amdgcn_fence(__ATOMIC_ACQUIRE, "agent");                                \
    }

  GROUP_SYNC(1);

  int cm = 16 * g + cn;           // chunk for A-frag rows
  for (int j = 0; j < 80; ++j) {
    int p = j & 1;
    const u16* st_r = stbuf + p * (128 * 1536);
    u16* st_w = stbuf + (1 - p) * (128 * 1536);
    // MFMA: [16 chunks,1536] @ [1536,16], K split over 4 waves
    f32x4 acc = {0.f, 0.f, 0.f, 0.f};
    bf16x8 areg[12];
    const u16* abase = st_r + cm * 1536 + q * 8;
    #pragma unroll
    for (int t = 0; t < 12; ++t)
      areg[t] = *(const bf16x8*)(abase + (wave * 12 + t) * 32);
    #pragma unroll
    for (int t = 0; t < 12; ++t) {
      int s = wave * 12 + t;
      bf16x8 bg = *(const bf16x8*)&wblob[(s * 64 + lane) * 8];
      acc = MFMA(areg[t], bg, acc);
    }
    #pragma unroll
    for (int r = 0; r < 4; ++r) red[wave][q * 4 + r][cn] = acc[r];
    __syncthreads();
    // epilogue: 256 threads = 16 chunks x 16 dims
    {
      int m = tid >> 4, col = tid & 15;
      int c = 16 * g + m, o = wgi * 16 + col;
      float sum = red[0][m][col] + red[1][m][col] + red[2][m][col] + red[3][m][col];
      int r = 16 * c - 64 + j;
      float val = 0.f;
      if (r >= 0) val = sum + delta[r * 768 + o];
      u32 oldw = *(const u32*)&st32[p * (128 * 768) + c * 768 + o];
      u32 neww = (u32)f2b(val) | (oldw << 16);
      __hip_atomic_store(&st32[(1 - p) * (128 * 768) + c * 768 + o], neww,
                         __ATOMIC_RELAXED, __HIP_MEMORY_SCOPE_AGENT);
      if (j >= 64) out[r * 768 + o] = val;
    }
    GROUP_SYNC(j + 2);
  }
  #undef GROUP_SYNC
}

// ---------------------------------------------------------------------------
extern "C" void kernel_launch(void* const* d_in, const int* in_sizes, int n_in,
                              void* d_out, int out_size, void* d_ws, size_t ws_size,
                              hipStream_t stream) {
  const float* u    = (const float*)d_in[0];   // [2048][768]
  const float* my   = (const float*)d_in[1];   // [768][2][768]
  const float* mu   = (const float*)d_in[2];   // [768][768][3]
  const float* mphi = (const float*)d_in[3];   // [18432][768]
  const float* ev   = (const float*)d_in[4];   // [24]
  const float* evec = (const float*)d_in[5];   // [2048][24]
  float* out = (float*)d_out;
  char* ws = (char*)d_ws;

  u16*   ub    = (u16*)(ws + WS_UB);
  u16*   mphiT = (u16*)(ws + WS_MPHIT);
  u16*   b2t   = (u16*)(ws + WS_B2T);
  u16*   tt    = (u16*)(ws + WS_TT);
  u16*   zt    = (u16*)(ws + WS_ZT);
  float* delta = (float*)(ws + WS_DELTA);
  u16*   stbuf = (u16*)(ws + WS_STBUF);
  int*   flags = (int*)(ws + WS_FLAGS);

  hipLaunchKernelGGL(k_zero,        dim3(1024),  dim3(256), 0, stream, delta, flags);
  hipLaunchKernelGGL(k_repack_u,    dim3(6150),  dim3(256), 0, stream, u, ub);
  hipLaunchKernelGGL(k_repack_mphi, dim3(13824), dim3(256), 0, stream, mphi, ev, mphiT);
  hipLaunchKernelGGL(k_repack_mu,   dim3(6912),  dim3(256), 0, stream, mu, b2t);
  hipLaunchKernelGGL(k_make_T,      dim3(24576), dim3(256), 0, stream, evec, tt);
  hipLaunchKernelGGL(k_gemm_zt,     dim3(2304),  dim3(256), 0, stream, mphiT, ub + 2 * 768, zt);
  hipLaunchKernelGGL(k_gemm_delta,  dim3(384),   dim3(256), 0, stream, tt, zt, ub, b2t, delta);
  hipLaunchKernelGGL(k_scan,        dim3(384),   dim3(256), 0, stream, my, delta, stbuf, flags, out);
}

// Round 3
// 1254.416 us; speedup vs baseline: 1.5571x; 1.5571x over previous
//
#include <hip/hip_runtime.h>
#include <hip/hip_bf16.h>
#include <stdint.h>

// STU forward: y = scan(m_y, (x_tilde @ m_phi) + AR(m_u, u))
// R3: R2 jump-recurrence structure with the &767 (non-pow2 mask) bug fixed in
// k_build_B / k_scan_init / k_scan_round.

typedef unsigned short u16;
typedef unsigned int   u32;
typedef __bf16  bf16x8 __attribute__((ext_vector_type(8)));
typedef float   f32x4  __attribute__((ext_vector_type(4)));
typedef u32     u32x4  __attribute__((ext_vector_type(4)));

#define MFMA(a,b,c) __builtin_amdgcn_mfma_f32_16x16x32_bf16(a,b,c,0,0,0)

__device__ __forceinline__ u16 f2b(float f) {           // fp32 -> bf16 bits, RNE
  union { float f; u32 u; } v; v.f = f;
  return (u16)((v.u + 0x7fffu + ((v.u >> 16) & 1u)) >> 16);
}

// ---------------- workspace layout (bytes) ----------------
// ub     : [2050][768] bf16                                @ 0
// mphiT  : [18432][768] bf16                               @ 3,148,800
// b2t    : [3][768][768] bf16                              @ 31,460,352
// tt     : [16][24][128][128] bf16                         @ 34,999,296
// zt     : [24][768][2048] bf16                            @ 47,582,208  (dead after k_gemm_delta)
// delta  : [2048][768] f32                                 @ 123,079,680
// --- overlay inside zt region (used only after k_gemm_delta) ---
#define WS_UB     0
#define WS_MPHIT  3148800
#define WS_B2T    31460352
#define WS_TT     34999296
#define WS_ZT     47582208
#define WS_DELTA  123079680
#define OV_DB     (WS_ZT + 0)
#define OV_UBIG   (WS_ZT + 3145728)
#define OV_TBIG   (WS_ZT + 13762560)
#define OV_VBIG   (WS_ZT + 24379392)
#define OV_A2T    (WS_ZT + 34996224)
#define OV_BWARM  (WS_ZT + 36175872)
#define OV_BOUT   (WS_ZT + 40894464)
#define OV_HBUF   (WS_ZT + 59768832)
#define OV_SBUF   (WS_ZT + 66060288)

// ---------------------------------------------------------------------------
__global__ void k_zero(float* __restrict__ delta) {
  int i = blockIdx.x * blockDim.x + threadIdx.x;
  int stride = gridDim.x * blockDim.x;
  for (int t = i; t < 2048 * 768; t += stride) delta[t] = 0.f;
}

__global__ void k_repack_u(const float* __restrict__ u, u16* __restrict__ ub) {
  int i = blockIdx.x * blockDim.x + threadIdx.x;
  if (i >= 2050 * 768) return;
  ub[i] = (i < 2 * 768) ? (u16)0 : f2b(u[i - 2 * 768]);
}

// mphiT[(k*768+d')][d] = eig_vals[k]^0.25 * m_phi[(k*768+d)][d']
__global__ void k_repack_mphi(const float* __restrict__ mphi, const float* __restrict__ ev,
                              u16* __restrict__ out) {
  __shared__ float tile[32][33];
  int bid = blockIdx.x;
  int k = bid / 576, rem = bid % 576;
  int ti = rem / 24, tj = rem % 24;
  int tid = threadIdx.x;
  int c = tid & 31, r0 = tid >> 5;
  float s = powf(ev[k], 0.25f);
  #pragma unroll
  for (int rr = 0; rr < 4; ++rr) {
    int r = r0 + (rr << 3);
    tile[r][c] = mphi[(k * 768 + ti * 32 + r) * 768 + tj * 32 + c];
  }
  __syncthreads();
  #pragma unroll
  for (int rr = 0; rr < 4; ++rr) {
    int r = r0 + (rr << 3);
    out[(k * 768 + tj * 32 + r) * 768 + ti * 32 + c] = f2b(tile[c][r] * s);
  }
}

__global__ void k_repack_mu(const float* __restrict__ mu, u16* __restrict__ out) {
  int i = blockIdx.x * blockDim.x + threadIdx.x;
  if (i >= 3 * 768 * 768) return;
  int kk = i / (768 * 768);
  int rem = i % (768 * 768);
  int o = rem / 768, ii = rem % 768;
  out[i] = f2b(mu[(o * 768 + ii) * 3 + kk]);
}

__global__ void k_make_T(const float* __restrict__ v, u16* __restrict__ out) {
  int i = blockIdx.x * blockDim.x + threadIdx.x;
  if (i >= 16 * 24 * 128 * 128) return;
  int c = i & 127, r = (i >> 7) & 127;
  int kk = (i >> 14) % 24, dlt = (i >> 14) / 24;
  int t = dlt * 128 + r - c - 2;
  out[i] = (t >= 0 && t < 2048) ? f2b(v[t * 24 + kk]) : (u16)0;
}

// ---------------------------------------------------------------------------
__device__ __forceinline__ void mfma_tile(const u16* As, const u16* Bs, int lane,
                                          int wm, int wn, f32x4 acc[4][4]) {
  #pragma unroll
  for (int ks = 0; ks < 2; ++ks) {
    int ko = ks * 32 + (lane >> 4) * 8;
    bf16x8 af[4], bg[4];
    #pragma unroll
    for (int i = 0; i < 4; ++i)
      af[i] = *(const bf16x8*)&As[(wm + i * 16 + (lane & 15)) * 64 + ko];
    #pragma unroll
    for (int j = 0; j < 4; ++j)
      bg[j] = *(const bf16x8*)&Bs[(wn + j * 16 + (lane & 15)) * 64 + ko];
    #pragma unroll
    for (int i = 0; i < 4; ++i)
      #pragma unroll
      for (int j = 0; j < 4; ++j)
        acc[i][j] = MFMA(af[i], bg[j], acc[i][j]);
  }
}

// K2: Zt[18432 x 2048] = mphiT @ ub^T
__global__ __launch_bounds__(256) void k_gemm_zt(const u16* __restrict__ A,
                                                 const u16* __restrict__ B,
                                                 u16* __restrict__ C) {
  __shared__ __align__(16) u16 As[128 * 64];
  __shared__ __align__(16) u16 Bs[128 * 64];
  int bid = blockIdx.x;
  int nt = bid & 15, mt = bid >> 4;
  int m0 = mt << 7, n0 = nt << 7;
  int tid = threadIdx.x, lane = tid & 63, wave = tid >> 6;
  int wm = (wave & 1) << 6, wn = (wave >> 1) << 6;
  int trow = tid >> 3, tcol = (tid & 7) << 3;
  f32x4 acc[4][4] = {};
  for (int kb = 0; kb < 12; ++kb) {
    int k0 = kb << 6;
    #pragma unroll
    for (int rr = 0; rr < 4; ++rr) {
      int row = trow + (rr << 5);
      *(u32x4*)&As[row * 64 + tcol] = *(const u32x4*)&A[(m0 + row) * 768 + k0 + tcol];
      *(u32x4*)&Bs[row * 64 + tcol] = *(const u32x4*)&B[(n0 + row) * 768 + k0 + tcol];
    }
    __syncthreads();
    mfma_tile(As, Bs, lane, wm, wn, acc);
    __syncthreads();
  }
  int q = lane >> 4, cn = lane & 15;
  #pragma unroll
  for (int i = 0; i < 4; ++i)
    #pragma unroll
    for (int j = 0; j < 4; ++j)
      #pragma unroll
      for (int r = 0; r < 4; ++r) {
        int m = m0 + wm + i * 16 + q * 4 + r;
        int n = n0 + wn + j * 16 + cn;
        C[m * 2048 + n] = f2b(acc[i][j][r]);
      }
}

// K3: delta = sum_k T_k @ Zt[k] + AR. Split-K=4, atomic f32 epilogue.
__global__ __launch_bounds__(256) void k_gemm_delta(const u16* __restrict__ tt,
                                                    const u16* __restrict__ zt,
                                                    const u16* __restrict__ ub,
                                                    const u16* __restrict__ b2t,
                                                    float* __restrict__ delta) {
  __shared__ __align__(16) u16 As[128 * 64];
  __shared__ __align__(16) u16 Bs[128 * 64];
  int bid = blockIdx.x;
  int sk = bid & 3;
  int r2 = bid >> 2;
  int db = r2 % 6;
  int lb = 15 - r2 / 6;
  int n0 = db << 7;
  int tid = threadIdx.x, lane = tid & 63, wave = tid >> 6;
  int wm = (wave & 1) << 6, wn = (wave >> 1) << 6;
  int trow = tid >> 3, tcol = (tid & 7) << 3;
  f32x4 acc[4][4] = {};
  for (int kk = sk * 6; kk < sk * 6 + 6; ++kk) {
    const u16* Bg = zt + kk * (768 * 2048);
    for (int th = 0; th < 2 * (lb + 1); ++th) {
      int tb = th >> 1, hf = th & 1;
      const u16* Ag = tt + ((lb - tb) * 24 + kk) * 16384;
      #pragma unroll
      for (int rr = 0; rr < 4; ++rr) {
        int row = trow + (rr << 5);
        *(u32x4*)&As[row * 64 + tcol] = *(const u32x4*)&Ag[row * 128 + hf * 64 + tcol];
        *(u32x4*)&Bs[row * 64 + tcol] =
            *(const u32x4*)&Bg[(n0 + row) * 2048 + tb * 128 + hf * 64 + tcol];
      }
      __syncthreads();
      mfma_tile(As, Bs, lane, wm, wn, acc);
      __syncthreads();
    }
  }
  if (sk < 3) {
    int kku = sk;
    const u16* Bg = b2t + kku * (768 * 768);
    for (int ic = 0; ic < 12; ++ic) {
      #pragma unroll
      for (int rr = 0; rr < 4; ++rr) {
        int row = trow + (rr << 5);
        *(u32x4*)&As[row * 64 + tcol] =
            *(const u32x4*)&ub[(2 + lb * 128 + row - kku) * 768 + ic * 64 + tcol];
        *(u32x4*)&Bs[row * 64 + tcol] =
            *(const u32x4*)&Bg[(n0 + row) * 768 + ic * 64 + tcol];
      }
      __syncthreads();
      mfma_tile(As, Bs, lane, wm, wn, acc);
      __syncthreads();
    }
  }
  int q = lane >> 4, cn = lane & 15;
  #pragma unroll
  for (int i = 0; i < 4; ++i)
    #pragma unroll
    for (int j = 0; j < 4; ++j)
      #pragma unroll
      for (int r = 0; r < 4; ++r) {
        int m = lb * 128 + wm + i * 16 + q * 4 + r;
        int n = n0 + wn + j * 16 + cn;
        unsafeAtomicAdd(&delta[m * 768 + n], acc[i][j][r]);
      }
}

// ---------------------------------------------------------------------------
// Scan-prep: U_0=I, U_1=A1, Vbig[1]=A2, Tbig[0]=I, Tbig[1]=A1^T, A2T=A2^T.
__global__ void k_init_UT(const float* __restrict__ my, u16* __restrict__ Ubig,
                          u16* __restrict__ Tbig, u16* __restrict__ Vbig,
                          u16* __restrict__ A2T) {
  int idx = blockIdx.x * blockDim.x + threadIdx.x;
  if (idx >= 768 * 768) return;
  int o = idx / 768, i = idx % 768;
  u16 a1 = f2b(my[o * 1536 + i]);
  u16 a2 = f2b(my[o * 1536 + 768 + i]);
  u16 id = (o == i) ? (u16)0x3F80 : (u16)0;
  Ubig[idx] = id;                         // U_0 = I
  Tbig[idx] = id;                         // T_0 = I
  Ubig[589824 + idx] = a1;                // U_1 = A1
  Tbig[589824 + i * 768 + o] = a1;        // T_1 = A1^T
  Vbig[589824 + idx] = a2;                // V_1 = A2 (also chain A2 operand)
  A2T[i * 768 + o] = a2;
}

// Chain: U_j = A1@U_{j-1} + A2@U_{j-2}. Writes U_j and T_j = U_j^T.
__global__ __launch_bounds__(256) void k_chain(const u16* __restrict__ A1r,
                                               const u16* __restrict__ A2r,
                                               const u16* __restrict__ Tp,
                                               const u16* __restrict__ Tp2,
                                               u16* __restrict__ Uout,
                                               u16* __restrict__ Tout) {
  __shared__ __align__(16) u16 As[128 * 64];
  __shared__ __align__(16) u16 Bs[128 * 64];
  int bid = blockIdx.x;
  int nt = bid % 6, mt = bid / 6;
  int m0 = mt << 7, n0 = nt << 7;
  int tid = threadIdx.x, lane = tid & 63, wave = tid >> 6;
  int wm = (wave & 1) << 6, wn = (wave >> 1) << 6;
  int trow = tid >> 3, tcol = (tid & 7) << 3;
  f32x4 acc[4][4] = {};
  for (int ph = 0; ph < 2; ++ph) {
    const u16* Ag = ph ? A2r : A1r;
    const u16* Bg = ph ? Tp2 : Tp;
    for (int kb = 0; kb < 12; ++kb) {
      int k0 = kb << 6;
      #pragma unroll
      for (int rr = 0; rr < 4; ++rr) {
        int row = trow + (rr << 5);
        *(u32x4*)&As[row * 64 + tcol] = *(const u32x4*)&Ag[(m0 + row) * 768 + k0 + tcol];
        *(u32x4*)&Bs[row * 64 + tcol] = *(const u32x4*)&Bg[(n0 + row) * 768 + k0 + tcol];
      }
      __syncthreads();
      mfma_tile(As, Bs, lane, wm, wn, acc);
      __syncthreads();
    }
  }
  int q = lane >> 4, cn = lane & 15;
  #pragma unroll
  for (int i = 0; i < 4; ++i)
    #pragma unroll
    for (int j = 0; j < 4; ++j) {
      int n = n0 + wn + j * 16 + cn;
      u16 pk[4];
      #pragma unroll
      for (int r = 0; r < 4; ++r) {
        int m = m0 + wm + i * 16 + q * 4 + r;
        u16 b = f2b(acc[i][j][r]);
        Uout[m * 768 + n] = b;
        pk[r] = b;
      }
      int mb = m0 + wm + i * 16 + q * 4;
      *(uint2*)&Tout[n * 768 + mb] = *(uint2*)pk;
    }
}

// Vbig[j] = U_{j-1} @ A2 for j=1..8: A = U_0..U_7 stacked (6144x768), B = A2T.
__global__ __launch_bounds__(256) void k_vbatch(const u16* __restrict__ Ubig,
                                                const u16* __restrict__ A2T,
                                                u16* __restrict__ Vbig) {
  __shared__ __align__(16) u16 As[128 * 64];
  __shared__ __align__(16) u16 Bs[128 * 64];
  int bid = blockIdx.x;
  int nt = bid % 6, mt = bid / 6;
  int m0 = mt << 7, n0 = nt << 7;
  int tid = threadIdx.x, lane = tid & 63, wave = tid >> 6;
  int wm = (wave & 1) << 6, wn = (wave >> 1) << 6;
  int trow = tid >> 3, tcol = (tid & 7) << 3;
  f32x4 acc[4][4] = {};
  for (int kb = 0; kb < 12; ++kb) {
    int k0 = kb << 6;
    #pragma unroll
    for (int rr = 0; rr < 4; ++rr) {
      int row = trow + (rr << 5);
      *(u32x4*)&As[row * 64 + tcol] = *(const u32x4*)&Ubig[(m0 + row) * 768 + k0 + tcol];
      *(u32x4*)&Bs[row * 64 + tcol] = *(const u32x4*)&A2T[(n0 + row) * 768 + k0 + tcol];
    }
    __syncthreads();
    mfma_tile(As, Bs, lane, wm, wn, acc);
    __syncthreads();
  }
  int q = lane >> 4, cn = lane & 15;
  #pragma unroll
  for (int i = 0; i < 4; ++i)
    #pragma unroll
    for (int j = 0; j < 4; ++j)
      #pragma unroll
      for (int r = 0; r < 4; ++r) {
        int m = m0 + wm + i * 16 + q * 4 + r;
        int n = n0 + wn + j * 16 + cn;
        Vbig[589824 + m * 768 + n] = f2b(acc[i][j][r]);
      }
}

// Bwarm[p][q] (p<768: [U_8 | V_8], else [U_7 | V_7]); Bout[j*768+o][q] = [U_{j+1} | V_{j+1}]
__global__ void k_build_B(const u16* __restrict__ Ubig, const u16* __restrict__ Vbig,
                          u16* __restrict__ Bwarm, u16* __restrict__ Bout) {
  int idx = blockIdx.x * blockDim.x + threadIdx.x;
  int row = idx / 192, cb = idx % 192;
  int q0 = cb * 8;
  int ju, po;
  u16* dst;
  if (row < 1536) {
    ju = (row < 768) ? 8 : 7;
    po = (row < 768) ? row : row - 768;        // FIX: was row & 767 (768 not pow2)
    dst = Bwarm + row * 1536 + q0;
  } else {
    int pr = row - 1536;
    ju = pr / 768 + 1;
    po = pr % 768;
    dst = Bout + pr * 1536 + q0;
  }
  const u16* src = (q0 < 768) ? (Ubig + ju * 589824 + po * 768 + q0)
                              : (Vbig + ju * 589824 + po * 768 + (q0 - 768));
  *(u32x4*)dst = *(const u32x4*)src;
}

__global__ void k_repack_db(const float* __restrict__ delta, u16* __restrict__ db) {
  int i = (blockIdx.x * blockDim.x + threadIdx.x) * 8;
  if (i >= 2048 * 768) return;
  u16 pk[8];
  #pragma unroll
  for (int j = 0; j < 8; ++j) pk[j] = f2b(delta[i + j]);
  *(u32x4*)&db[i] = *(u32x4*)pk;
}

// H[t][o] = sum_{i<=t&7} U_i[o][:] . d[t-i][:]   — masked-window GEMM, K=6144.
__global__ __launch_bounds__(256) void k_conv(const u16* __restrict__ db,
                                              const u16* __restrict__ Ubig,
                                              float* __restrict__ Hbuf) {
  __shared__ __align__(16) u16 As[128 * 64];
  __shared__ __align__(16) u16 Bs[128 * 64];
  int bid = blockIdx.x;
  int nt = bid % 6, mt = bid / 6;
  int m0 = mt << 7, n0 = nt << 7;
  int tid = threadIdx.x, lane = tid & 63, wave = tid >> 6;
  int wm = (wave & 1) << 6, wn = (wave >> 1) << 6;
  int trow = tid >> 3, tcol = (tid & 7) << 3;
  f32x4 acc[4][4] = {};
  for (int kb = 0; kb < 96; ++kb) {
    int i = kb / 12, dinb = kb % 12;
    #pragma unroll
    for (int rr = 0; rr < 4; ++rr) {
      int row = trow + (rr << 5);
      int t = m0 + row;
      u32x4 va = {0u, 0u, 0u, 0u};
      if (i <= (t & 7))
        va = *(const u32x4*)&db[(t - i) * 768 + dinb * 64 + tcol];
      *(u32x4*)&As[row * 64 + tcol] = va;
      *(u32x4*)&Bs[row * 64 + tcol] =
          *(const u32x4*)&Ubig[i * 589824 + (n0 + row) * 768 + dinb * 64 + tcol];
    }
    __syncthreads();
    mfma_tile(As, Bs, lane, wm, wn, acc);
    __syncthreads();
  }
  int q = lane >> 4, cn = lane & 15;
  #pragma unroll
  for (int i = 0; i < 4; ++i)
    #pragma unroll
    for (int j = 0; j < 4; ++j)
      #pragma unroll
      for (int r = 0; r < 4; ++r) {
        int m = m0 + wm + i * 16 + q * 4 + r;
        int n = n0 + wn + j * 16 + cn;
        Hbuf[m * 768 + n] = acc[i][j][r];
      }
}

// S0[c] = (y_{8c-25}, y_{8c-26}) approx by H rows (0 if t<0)
__global__ void k_scan_init(const float* __restrict__ Hbuf, u16* __restrict__ S0) {
  int idx = blockIdx.x * blockDim.x + threadIdx.x;
  if (idx >= 256 * 1536) return;
  int c = idx / 1536, q = idx % 1536;
  int t = 8 * c - 25 - (q < 768 ? 0 : 1);
  int o = (q < 768) ? q : q - 768;             // FIX: was q & 767
  S0[idx] = (t >= 0) ? f2b(Hbuf[t * 768 + o]) : (u16)0;
}

// warm-up jump: Snew[c] = Bwarm @ Sold[c] + (H[8c+hoff], H[8c+hoff-1])
__global__ __launch_bounds__(256) void k_scan_round(const u16* __restrict__ Sin,
                                                    const u16* __restrict__ Bw,
                                                    const float* __restrict__ Hbuf,
                                                    u16* __restrict__ Sout, int hoff) {
  __shared__ __align__(16) u16 As[128 * 64];
  __shared__ __align__(16) u16 Bs[128 * 64];
  int bid = blockIdx.x;
  int nt = bid % 12, mt = bid / 12;
  int m0 = mt << 7, n0 = nt << 7;
  int tid = threadIdx.x, lane = tid & 63, wave = tid >> 6;
  int wm = (wave & 1) << 6, wn = (wave >> 1) << 6;
  int trow = tid >> 3, tcol = (tid & 7) << 3;
  f32x4 acc[4][4] = {};
  for (int kb = 0; kb < 24; ++kb) {
    int k0 = kb << 6;
    #pragma unroll
    for (int rr = 0; rr < 4; ++rr) {
      int row = trow + (rr << 5);
      *(u32x4*)&As[row * 64 + tcol] = *(const u32x4*)&Sin[(m0 + row) * 1536 + k0 + tcol];
      *(u32x4*)&Bs[row * 64 + tcol] = *(const u32x4*)&Bw[(n0 + row) * 1536 + k0 + tcol];
    }
    __syncthreads();
    mfma_tile(As, Bs, lane, wm, wn, acc);
    __syncthreads();
  }
  int q = lane >> 4, cn = lane & 15;
  #pragma unroll
  for (int i = 0; i < 4; ++i)
    #pragma unroll
    for (int j = 0; j < 4; ++j)
      #pragma unroll
      for (int r = 0; r < 4; ++r) {
        int c = m0 + wm + i * 16 + q * 4 + r;
        int n = n0 + wn + j * 16 + cn;
        int t = 8 * c + hoff - (n < 768 ? 0 : 1);
        int o = (n < 768) ? n : n - 768;       // FIX: was n & 767
        float val = acc[i][j][r] + ((t >= 0) ? Hbuf[t * 768 + o] : 0.f);
        Sout[c * 1536 + n] = f2b(val);
      }
}

// output round: y[8c+jj] = (Bout @ S[c])[jj*768+o] + H[8c+jj]
__global__ __launch_bounds__(256) void k_scan_out(const u16* __restrict__ Sin,
                                                  const u16* __restrict__ Bo,
                                                  const float* __restrict__ Hbuf,
                                                  float* __restrict__ out) {
  __shared__ __align__(16) u16 As[128 * 64];
  __shared__ __align__(16) u16 Bs[128 * 64];
  int bid = blockIdx.x;
  int nt = bid % 48, mt = bid / 48;
  int m0 = mt << 7, n0 = nt << 7;
  int tid = threadIdx.x, lane = tid & 63, wave = tid >> 6;
  int wm = (wave & 1) << 6, wn = (wave >> 1) << 6;
  int trow = tid >> 3, tcol = (tid & 7) << 3;
  f32x4 acc[4][4] = {};
  for (int kb = 0; kb < 24; ++kb) {
    int k0 = kb << 6;
    #pragma unroll
    for (int rr = 0; rr < 4; ++rr) {
      int row = trow + (rr << 5);
      *(u32x4*)&As[row * 64 + tcol] = *(const u32x4*)&Sin[(m0 + row) * 1536 + k0 + tcol];
      *(u32x4*)&Bs[row * 64 + tcol] = *(const u32x4*)&Bo[(n0 + row) * 1536 + k0 + tcol];
    }
    __syncthreads();
    mfma_tile(As, Bs, lane, wm, wn, acc);
    __syncthreads();
  }
  int q = lane >> 4, cn = lane & 15;
  #pragma unroll
  for (int i = 0; i < 4; ++i)
    #pragma unroll
    for (int j = 0; j < 4; ++j)
      #pragma unroll
      for (int r = 0; r < 4; ++r) {
        int c = m0 + wm + i * 16 + q * 4 + r;
        int n = n0 + wn + j * 16 + cn;
        int jj = n / 768, o = n % 768;
        int t = 8 * c + jj;
        out[t * 768 + o] = acc[i][j][r] + Hbuf[t * 768 + o];
      }
}

// ---------------------------------------------------------------------------
extern "C" void kernel_launch(void* const* d_in, const int* in_sizes, int n_in,
                              void* d_out, int out_size, void* d_ws, size_t ws_size,
                              hipStream_t stream) {
  const float* u    = (const float*)d_in[0];
  const float* my   = (const float*)d_in[1];
  const float* mu   = (const float*)d_in[2];
  const float* mphi = (const float*)d_in[3];
  const float* ev   = (const float*)d_in[4];
  const float* evec = (const float*)d_in[5];
  float* out = (float*)d_out;
  char* ws = (char*)d_ws;

  u16*   ub    = (u16*)(ws + WS_UB);
  u16*   mphiT = (u16*)(ws + WS_MPHIT);
  u16*   b2t   = (u16*)(ws + WS_B2T);
  u16*   tt    = (u16*)(ws + WS_TT);
  u16*   zt    = (u16*)(ws + WS_ZT);
  float* delta = (float*)(ws + WS_DELTA);
  u16*   db    = (u16*)(ws + OV_DB);
  u16*   Ubig  = (u16*)(ws + OV_UBIG);
  u16*   Tbig  = (u16*)(ws + OV_TBIG);
  u16*   Vbig  = (u16*)(ws + OV_VBIG);
  u16*   A2T   = (u16*)(ws + OV_A2T);
  u16*   Bwarm = (u16*)(ws + OV_BWARM);
  u16*   Bout  = (u16*)(ws + OV_BOUT);
  float* Hbuf  = (float*)(ws + OV_HBUF);
  u16*   S0    = (u16*)(ws + OV_SBUF);
  u16*   S1    = S0 + 256 * 1536;

  hipLaunchKernelGGL(k_zero,        dim3(1024),  dim3(256), 0, stream, delta);
  hipLaunchKernelGGL(k_repack_u,    dim3(6150),  dim3(256), 0, stream, u, ub);
  hipLaunchKernelGGL(k_repack_mphi, dim3(13824), dim3(256), 0, stream, mphi, ev, mphiT);
  hipLaunchKernelGGL(k_repack_mu,   dim3(6912),  dim3(256), 0, stream, mu, b2t);
  hipLaunchKernelGGL(k_make_T,      dim3(24576), dim3(256), 0, stream, evec, tt);
  hipLaunchKernelGGL(k_gemm_zt,     dim3(2304),  dim3(256), 0, stream, mphiT, ub + 2 * 768, zt);
  hipLaunchKernelGGL(k_gemm_delta,  dim3(384),   dim3(256), 0, stream, tt, zt, ub, b2t, delta);

  // --- scan prep (overlays zt region; stream-ordered after k_gemm_delta) ---
  hipLaunchKernelGGL(k_init_UT, dim3(2304), dim3(256), 0, stream, my, Ubig, Tbig, Vbig, A2T);
  u16* A1r = Ubig + 589824;      // U_1 = A1 rows
  u16* A2r = Vbig + 589824;      // V_1 = A2 rows
  for (int j = 2; j <= 8; ++j) {
    hipLaunchKernelGGL(k_chain, dim3(36), dim3(256), 0, stream, A1r, A2r,
                       Tbig + (j - 1) * 589824, Tbig + (j - 2) * 589824,
                       Ubig + j * 589824, Tbig + j * 589824);
  }
  hipLaunchKernelGGL(k_vbatch,    dim3(288),  dim3(256), 0, stream, Ubig, A2T, Vbig);
  hipLaunchKernelGGL(k_build_B,   dim3(5760), dim3(256), 0, stream, Ubig, Vbig, Bwarm, Bout);
  hipLaunchKernelGGL(k_repack_db, dim3(768),  dim3(256), 0, stream, delta, db);
  hipLaunchKernelGGL(k_conv,      dim3(96),   dim3(256), 0, stream, db, Ubig, Hbuf);

  // --- scan: init + 3 warm-up jumps + output ---
  hipLaunchKernelGGL(k_scan_init, dim3(1536), dim3(256), 0, stream, Hbuf, S0);
  hipLaunchKernelGGL(k_scan_round, dim3(24), dim3(256), 0, stream, S0, Bwarm, Hbuf, S1, -17);
  hipLaunchKernelGGL(k_scan_round, dim3(24), dim3(256), 0, stream, S1, Bwarm, Hbuf, S0, -9);
  hipLaunchKernelGGL(k_scan_round, dim3(24), dim3(256), 0, stream, S0, Bwarm, Hbuf, S1, -1);
  hipLaunchKernelGGL(k_scan_out,  dim3(96),  dim3(256), 0, stream, S1, Bout, Hbuf, out);
}

// Round 4
// 673.523 us; speedup vs baseline: 2.9001x; 1.8625x over previous
//
#include <hip/hip_runtime.h>
#include <hip/hip_bf16.h>
#include <stdint.h>

// STU forward: y = scan(m_y, (x_tilde @ m_phi) + AR(m_u, u))
// R4: async global_load_lds(16B) staging + XOR-swizzled LDS reads in all GEMMs;
// balanced split-K k_gemm_delta (816 blocks); chain-by-doubling (3 batched GEMMs);
// k_conv split-K=4. Scan B-operands read directly from R storage (no copies).

typedef unsigned short u16;
typedef unsigned int   u32;
typedef __bf16  bf16x8 __attribute__((ext_vector_type(8)));
typedef float   f32x4  __attribute__((ext_vector_type(4)));
typedef u32     u32x4  __attribute__((ext_vector_type(4)));

#define MFMA(a,b,c) __builtin_amdgcn_mfma_f32_16x16x32_bf16(a,b,c,0,0,0)
#define RJ 1179648   // elems per R_j (768*1536)

__device__ __forceinline__ u16 f2b(float f) {           // fp32 -> bf16 bits, RNE
  union { float f; u32 u; } v; v.f = f;
  return (u16)((v.u + 0x7fffu + ((v.u >> 16) & 1u)) >> 16);
}

__device__ __forceinline__ void gld16(const u16* g, u16* l) {
  __builtin_amdgcn_global_load_lds(
      (const __attribute__((address_space(1))) u32*)g,
      (__attribute__((address_space(3))) u32*)l, 16, 0, 0);
}

// ---------------- workspace layout (bytes) ----------------
#define WS_UB     0           // [2050][768] bf16
#define WS_MPHIT  3148800     // [18432][768] bf16
#define WS_B2T    31460352    // [3][768][768] bf16
#define WS_TT     34999296    // [16][24][128][128] bf16
#define WS_ZT     47582208    // [24][768][2048] bf16 (dead after k_gemm_delta)
#define WS_DELTA  123079680   // [2048][768] f32
// overlay inside zt region (used only after k_gemm_delta):
#define OV_DB     (WS_ZT + 0)          // [2048][768] bf16
#define OV_RBIG   (WS_ZT + 3145728)    // [9][768][1536] bf16  R_j = [U_j | V_j]
#define OV_CT     (WS_ZT + 24379392)   // [1536][1536] bf16    (C^delta)^T scratch
#define OV_HBUF   (WS_ZT + 29097984)   // [2048][768] f32
#define OV_SBUF   (WS_ZT + 35389440)   // [2][256][1536] bf16

// ---------------------------------------------------------------------------
__global__ void k_zero(float* __restrict__ delta) {
  int i = blockIdx.x * blockDim.x + threadIdx.x;
  int stride = gridDim.x * blockDim.x;
  for (int t = i; t < 2048 * 768; t += stride) delta[t] = 0.f;
}

__global__ void k_zeroH(float* __restrict__ H) {
  int i = blockIdx.x * blockDim.x + threadIdx.x;
  int stride = gridDim.x * blockDim.x;
  for (int t = i; t < 2048 * 768; t += stride) H[t] = 0.f;
}

__global__ void k_repack_u(const float* __restrict__ u, u16* __restrict__ ub) {
  int i = blockIdx.x * blockDim.x + threadIdx.x;
  if (i >= 2050 * 768) return;
  ub[i] = (i < 2 * 768) ? (u16)0 : f2b(u[i - 2 * 768]);
}

// mphiT[(k*768+d')][d] = eig_vals[k]^0.25 * m_phi[(k*768+d)][d']
__global__ void k_repack_mphi(const float* __restrict__ mphi, const float* __restrict__ ev,
                              u16* __restrict__ out) {
  __shared__ float tile[32][33];
  int bid = blockIdx.x;
  int k = bid / 576, rem = bid % 576;
  int ti = rem / 24, tj = rem % 24;
  int tid = threadIdx.x;
  int c = tid & 31, r0 = tid >> 5;
  float s = powf(ev[k], 0.25f);
  #pragma unroll
  for (int rr = 0; rr < 4; ++rr) {
    int r = r0 + (rr << 3);
    tile[r][c] = mphi[(k * 768 + ti * 32 + r) * 768 + tj * 32 + c];
  }
  __syncthreads();
  #pragma unroll
  for (int rr = 0; rr < 4; ++rr) {
    int r = r0 + (rr << 3);
    out[(k * 768 + tj * 32 + r) * 768 + ti * 32 + c] = f2b(tile[c][r] * s);
  }
}

__global__ void k_repack_mu(const float* __restrict__ mu, u16* __restrict__ out) {
  int i = blockIdx.x * blockDim.x + threadIdx.x;
  if (i >= 3 * 768 * 768) return;
  int kk = i / (768 * 768);
  int rem = i % (768 * 768);
  int o = rem / 768, ii = rem % 768;
  out[i] = f2b(mu[(o * 768 + ii) * 3 + kk]);
}

__global__ void k_make_T(const float* __restrict__ v, u16* __restrict__ out) {
  int i = blockIdx.x * blockDim.x + threadIdx.x;
  if (i >= 16 * 24 * 128 * 128) return;
  int c = i & 127, r = (i >> 7) & 127;
  int kk = (i >> 14) % 24, dlt = (i >> 14) / 24;
  int t = dlt * 128 + r - c - 2;
  out[i] = (t >= 0 && t < 2048) ? f2b(v[t * 24 + kk]) : (u16)0;
}

// ---------------------------------------------------------------------------
// Stage 128 rows x 64 u16 tile (16 KB) via async global_load_lds, XOR-swizzled:
// LDS slot (row, cb) holds global (row, cb ^ (row&7)).  256 threads.
__device__ __forceinline__ void stage128(const u16* __restrict__ g, int ld,
                                         u16* __restrict__ lds) {
  int tid = threadIdx.x;
  int r0 = tid >> 3, cb = tid & 7, wave = tid >> 6;
  #pragma unroll
  for (int s = 0; s < 4; ++s) {
    int row = r0 + (s << 5);
    int cbx = (cb ^ (row & 7)) << 3;
    gld16(g + row * ld + cbx, lds + (s << 11) + (wave << 9));
  }
}

// Swizzle-aware fragment reads + 16 MFMA (K=64 slab).
__device__ __forceinline__ void mfma_tile(const u16* As, const u16* Bs, int lane,
                                          int wm, int wn, f32x4 acc[4][4]) {
  int cn = lane & 15, q = lane >> 4;
  #pragma unroll
  for (int ks = 0; ks < 2; ++ks) {
    int blk = ks * 4 + q;
    bf16x8 af[4], bg[4];
    #pragma unroll
    for (int i = 0; i < 4; ++i) {
      int row = wm + i * 16 + cn;
      af[i] = *(const bf16x8*)&As[row * 64 + ((blk ^ (row & 7)) << 3)];
    }
    #pragma unroll
    for (int j = 0; j < 4; ++j) {
      int row = wn + j * 16 + cn;
      bg[j] = *(const bf16x8*)&Bs[row * 64 + ((blk ^ (row & 7)) << 3)];
    }
    #pragma unroll
    for (int i = 0; i < 4; ++i)
      #pragma unroll
      for (int j = 0; j < 4; ++j)
        acc[i][j] = MFMA(af[i], bg[j], acc[i][j]);
  }
}

// K2: Zt[18432 x 2048] = mphiT @ ub^T
__global__ __launch_bounds__(256) void k_gemm_zt(const u16* __restrict__ A,
                                                 const u16* __restrict__ B,
                                                 u16* __restrict__ C) {
  __shared__ __align__(16) u16 As[128 * 64];
  __shared__ __align__(16) u16 Bs[128 * 64];
  int bid = blockIdx.x;
  int nt = bid & 15, mt = bid >> 4;
  int m0 = mt << 7, n0 = nt << 7;
  int tid = threadIdx.x, lane = tid & 63, wave = tid >> 6;
  int wm = (wave & 1) << 6, wn = (wave >> 1) << 6;
  f32x4 acc[4][4] = {};
  for (int kb = 0; kb < 12; ++kb) {
    stage128(A + m0 * 768 + kb * 64, 768, As);
    stage128(B + n0 * 768 + kb * 64, 768, Bs);
    __syncthreads();
    mfma_tile(As, Bs, lane, wm, wn, acc);
    __syncthreads();
  }
  int q = lane >> 4, cn = lane & 15;
  #pragma unroll
  for (int i = 0; i < 4; ++i)
    #pragma unroll
    for (int j = 0; j < 4; ++j)
      #pragma unroll
      for (int r = 0; r < 4; ++r) {
        int m = m0 + wm + i * 16 + q * 4 + r;
        int n = n0 + wn + j * 16 + cn;
        C[m * 2048 + n] = f2b(acc[i][j][r]);
      }
}

// K3: delta = sum_k T_k @ Zt[k] + AR.  Balanced split: block = (db, lb, s=t-block).
__global__ __launch_bounds__(256) void k_gemm_delta(const u16* __restrict__ tt,
                                                    const u16* __restrict__ zt,
                                                    const u16* __restrict__ ub,
                                                    const u16* __restrict__ b2t,
                                                    float* __restrict__ delta) {
  __shared__ __align__(16) u16 As[128 * 64];
  __shared__ __align__(16) u16 Bs[128 * 64];
  int bid = blockIdx.x;
  int db = bid % 6;
  int r = bid / 6;                 // 0..135 -> (lb, s): r = lb(lb+1)/2 + s
  int lb = 0, s = 0;
  for (;; ++lb) { if (r <= lb) { s = r; break; } r -= lb + 1; }
  int n0 = db << 7;
  int tid = threadIdx.x, lane = tid & 63, wave = tid >> 6;
  int wm = (wave & 1) << 6, wn = (wave >> 1) << 6;
  f32x4 acc[4][4] = {};
  const u16* Ag0 = tt + (lb - s) * 24 * 16384;
  for (int kk = 0; kk < 24; ++kk) {
    const u16* Ag = Ag0 + kk * 16384;
    const u16* Bg = zt + kk * (768 * 2048) + n0 * 2048 + s * 128;
    #pragma unroll
    for (int hf = 0; hf < 2; ++hf) {
      stage128(Ag + hf * 64, 128, As);
      stage128(Bg + hf * 64, 2048, Bs);
      __syncthreads();
      mfma_tile(As, Bs, lane, wm, wn, acc);
      __syncthreads();
    }
  }
  // AR taps: tap kku owned by split s == min(kku, lb)
  #pragma unroll
  for (int kku = 0; kku < 3; ++kku) {
    int owner = (kku <= lb) ? kku : lb;
    if (s != owner) continue;
    const u16* Au = ub + (2 + lb * 128 - kku) * 768;
    const u16* Bg = b2t + kku * (768 * 768) + n0 * 768;
    for (int ic = 0; ic < 12; ++ic) {
      stage128(Au + ic * 64, 768, As);
      stage128(Bg + ic * 64, 768, Bs);
      __syncthreads();
      mfma_tile(As, Bs, lane, wm, wn, acc);
      __syncthreads();
    }
  }
  int q = lane >> 4, cn = lane & 15;
  #pragma unroll
  for (int i = 0; i < 4; ++i)
    #pragma unroll
    for (int j = 0; j < 4; ++j)
      #pragma unroll
      for (int rr = 0; rr < 4; ++rr) {
        int m = lb * 128 + wm + i * 16 + q * 4 + rr;
        int n = n0 + wn + j * 16 + cn;
        unsafeAtomicAdd(&delta[m * 768 + n], acc[i][j][rr]);
      }
}

// ---------------------------------------------------------------------------
// R_0 = [I | 0], R_1 = [A1 | A2] = f2b(m_y rows)
__global__ void k_buildR01(const float* __restrict__ my, u16* __restrict__ R0,
                           u16* __restrict__ R1) {
  int i = blockIdx.x * blockDim.x + threadIdx.x;
  if (i >= 768 * 1536) return;
  int o = i / 1536, q = i % 1536;
  R0[i] = (q == o) ? (u16)0x3F80 : (u16)0;
  R1[i] = f2b(my[i]);
}

// Ct[n][p] = (p<768 ? Rhi[p][n] : Rlo[p-768][n])   ((C^delta)^T, 1536x1536)
__global__ void k_buildCt(const u16* __restrict__ Rhi, const u16* __restrict__ Rlo,
                          u16* __restrict__ Ct) {
  __shared__ u16 tile[64][72];
  int bid = blockIdx.x;                 // 24 x 24 tiles of 64^2
  int pt = bid % 24, nt = bid / 24;
  int p0 = pt * 64, n0 = nt * 64;
  int tid = threadIdx.x;
  int rr = tid & 63, c0 = (tid >> 6) * 16;
  const u16* src = ((p0 + rr) < 768) ? (Rhi + (p0 + rr) * 1536)
                                     : (Rlo + (p0 + rr - 768) * 1536);
  *(u32x4*)&tile[rr][c0]     = *(const u32x4*)&src[n0 + c0];
  *(u32x4*)&tile[rr][c0 + 8] = *(const u32x4*)&src[n0 + c0 + 8];
  __syncthreads();
  u16 pk[16];
  #pragma unroll
  for (int j = 0; j < 16; ++j) pk[j] = tile[c0 + j][rr];
  *(u32x4*)&Ct[(n0 + rr) * 1536 + p0 + c0]     = *(u32x4*)pk;
  *(u32x4*)&Ct[(n0 + rr) * 1536 + p0 + c0 + 8] = *(u32x4*)&pk[8];
}

// Generic M x 1536 x 1536: Co[m][n] = sum_p A[m][p] * Ct[n][p]
__global__ __launch_bounds__(256) void k_gemm_R(const u16* __restrict__ A,
                                                const u16* __restrict__ Ct,
                                                u16* __restrict__ Co) {
  __shared__ __align__(16) u16 As[128 * 64];
  __shared__ __align__(16) u16 Bs[128 * 64];
  int bid = blockIdx.x;
  int nt = bid % 12, mt = bid / 12;
  int m0 = mt << 7, n0 = nt << 7;
  int tid = threadIdx.x, lane = tid & 63, wave = tid >> 6;
  int wm = (wave & 1) << 6, wn = (wave >> 1) << 6;
  f32x4 acc[4][4] = {};
  for (int kb = 0; kb < 24; ++kb) {
    stage128(A + m0 * 1536 + kb * 64, 1536, As);
    stage128(Ct + n0 * 1536 + kb * 64, 1536, Bs);
    __syncthreads();
    mfma_tile(As, Bs, lane, wm, wn, acc);
    __syncthreads();
  }
  int q = lane >> 4, cn = lane & 15;
  #pragma unroll
  for (int i = 0; i < 4; ++i)
    #pragma unroll
    for (int j = 0; j < 4; ++j)
      #pragma unroll
      for (int r = 0; r < 4; ++r) {
        int m = m0 + wm + i * 16 + q * 4 + r;
        int n = n0 + wn + j * 16 + cn;
        Co[m * 1536 + n] = f2b(acc[i][j][r]);
      }
}

__global__ void k_repack_db(const float* __restrict__ delta, u16* __restrict__ db) {
  int i = (blockIdx.x * blockDim.x + threadIdx.x) * 8;
  if (i >= 2048 * 768) return;
  u16 pk[8];
  #pragma unroll
  for (int j = 0; j < 8; ++j) pk[j] = f2b(delta[i + j]);
  *(u32x4*)&db[i] = *(u32x4*)pk;
}

// H[t][o] = sum_{i<=t&7} U_i[o][:] . d[t-i][:]  — split-K=4 over i-pairs, atomics.
__global__ __launch_bounds__(256) void k_conv(const u16* __restrict__ db,
                                              const u16* __restrict__ Rbig,
                                              float* __restrict__ Hbuf) {
  __shared__ __align__(16) u16 As[128 * 64];
  __shared__ __align__(16) u16 Bs[128 * 64];
  int bid = blockIdx.x;
  int nt = bid % 6, mt = (bid / 6) % 16, sp = bid / 96;
  int m0 = mt << 7, n0 = nt << 7;
  int tid = threadIdx.x, lane = tid & 63, wave = tid >> 6;
  int wm = (wave & 1) << 6, wn = (wave >> 1) << 6;
  int trow = tid >> 3, cb = tid & 7;
  f32x4 acc[4][4] = {};
  for (int kb = 0; kb < 24; ++kb) {
    int i = 2 * sp + kb / 12, dinb = kb % 12;
    // A: masked VGPR staging (can't mask async path), swizzled LDS write
    #pragma unroll
    for (int s = 0; s < 4; ++s) {
      int row = trow + (s << 5);
      int t = m0 + row;
      u32x4 va = {0u, 0u, 0u, 0u};
      if (i <= (t & 7))
        va = *(const u32x4*)&db[(t - i) * 768 + dinb * 64 + (cb << 3)];
      *(u32x4*)&As[row * 64 + ((cb ^ (row & 7)) << 3)] = va;
    }
    // B: U_i rows = Rbig[i] cols 0..767 (row stride 1536)
    stage128(Rbig + i * RJ + n0 * 1536 + dinb * 64, 1536, Bs);
    __syncthreads();
    mfma_tile(As, Bs, lane, wm, wn, acc);
    __syncthreads();
  }
  int q = lane >> 4, cn = lane & 15;
  #pragma unroll
  for (int i = 0; i < 4; ++i)
    #pragma unroll
    for (int j = 0; j < 4; ++j)
      #pragma unroll
      for (int r = 0; r < 4; ++r) {
        int m = m0 + wm + i * 16 + q * 4 + r;
        int n = n0 + wn + j * 16 + cn;
        unsafeAtomicAdd(&Hbuf[m * 768 + n], acc[i][j][r]);
      }
}

// S0[c] = (H[8c-25], H[8c-26])  (0 if t<0)
__global__ void k_scan_init(const float* __restrict__ Hbuf, u16* __restrict__ S0) {
  int idx = blockIdx.x * blockDim.x + threadIdx.x;
  if (idx >= 256 * 1536) return;
  int c = idx / 1536, q = idx % 1536;
  int t = 8 * c - 25 - (q < 768 ? 0 : 1);
  int o = (q < 768) ? q : q - 768;
  S0[idx] = (t >= 0) ? f2b(Hbuf[t * 768 + o]) : (u16)0;
}

// warm-up jump: Snew[c] = W @ Sold[c] + (H[8c+hoff], H[8c+hoff-1]);
// W rows: n<768 -> R_8[n], else R_7[n-768]  (read in place from Rbig)
__global__ __launch_bounds__(256) void k_scan_round(const u16* __restrict__ Sin,
                                                    const u16* __restrict__ Rbig,
                                                    const float* __restrict__ Hbuf,
                                                    u16* __restrict__ Sout, int hoff) {
  __shared__ __align__(16) u16 As[128 * 64];
  __shared__ __align__(16) u16 Bs[128 * 64];
  int bid = blockIdx.x;
  int nt = bid % 12, mt = bid / 12;
  int m0 = mt << 7, n0 = nt << 7;
  const u16* Bg = (nt < 6) ? (Rbig + 8 * RJ + n0 * 1536)
                           : (Rbig + 7 * RJ + (n0 - 768) * 1536);
  int tid = threadIdx.x, lane = tid & 63, wave = tid >> 6;
  int wm = (wave & 1) << 6, wn = (wave >> 1) << 6;
  f32x4 acc[4][4] = {};
  for (int kb = 0; kb < 24; ++kb) {
    stage128(Sin + m0 * 1536 + kb * 64, 1536, As);
    stage128(Bg + kb * 64, 1536, Bs);
    __syncthreads();
    mfma_tile(As, Bs, lane, wm, wn, acc);
    __syncthreads();
  }
  int q = lane >> 4, cn = lane & 15;
  #pragma unroll
  for (int i = 0; i < 4; ++i)
    #pragma unroll
    for (int j = 0; j < 4; ++j)
      #pragma unroll
      for (int r = 0; r < 4; ++r) {
        int c = m0 + wm + i * 16 + q * 4 + r;
        int n = n0 + wn + j * 16 + cn;
        int t = 8 * c + hoff - (n < 768 ? 0 : 1);
        int o = (n < 768) ? n : n - 768;
        float val = acc[i][j][r] + ((t >= 0) ? Hbuf[t * 768 + o] : 0.f);
        Sout[c * 1536 + n] = f2b(val);
      }
}

// output: y[8c+jj] = (R_{jj+1} @ S[c])[o] + H[8c+jj][o];  B rows from Rbig[1..8]
__global__ __launch_bounds__(256) void k_scan_out(const u16* __restrict__ Sin,
                                                  const u16* __restrict__ Rbig,
                                                  const float* __restrict__ Hbuf,
                                                  float* __restrict__ out) {
  __shared__ __align__(16) u16 As[128 * 64];
  __shared__ __align__(16) u16 Bs[128 * 64];
  int bid = blockIdx.x;
  int nt = bid % 48, mt = bid / 48;
  int m0 = mt << 7, n0 = nt << 7;
  const u16* Bg = Rbig + RJ + n0 * 1536;   // rows of [R_1; ...; R_8]
  int tid = threadIdx.x, lane = tid & 63, wave = tid >> 6;
  int wm = (wave & 1) << 6, wn = (wave >> 1) << 6;
  f32x4 acc[4][4] = {};
  for (int kb = 0; kb < 24; ++kb) {
    stage128(Sin + m0 * 1536 + kb * 64, 1536, As);
    stage128(Bg + kb * 64, 1536, Bs);
    __syncthreads();
    mfma_tile(As, Bs, lane, wm, wn, acc);
    __syncthreads();
  }
  int q = lane >> 4, cn = lane & 15;
  #pragma unroll
  for (int i = 0; i < 4; ++i)
    #pragma unroll
    for (int j = 0; j < 4; ++j)
      #pragma unroll
      for (int r = 0; r < 4; ++r) {
        int c = m0 + wm + i * 16 + q * 4 + r;
        int n = n0 + wn + j * 16 + cn;
        int jj = n / 768, o = n % 768;
        int t = 8 * c + jj;
        out[t * 768 + o] = acc[i][j][r] + Hbuf[t * 768 + o];
      }
}

// ---------------------------------------------------------------------------
extern "C" void kernel_launch(void* const* d_in, const int* in_sizes, int n_in,
                              void* d_out, int out_size, void* d_ws, size_t ws_size,
                              hipStream_t stream) {
  const float* u    = (const float*)d_in[0];
  const float* my   = (const float*)d_in[1];
  const float* mu   = (const float*)d_in[2];
  const float* mphi = (const float*)d_in[3];
  const float* ev   = (const float*)d_in[4];
  const float* evec = (const float*)d_in[5];
  float* out = (float*)d_out;
  char* ws = (char*)d_ws;

  u16*   ub    = (u16*)(ws + WS_UB);
  u16*   mphiT = (u16*)(ws + WS_MPHIT);
  u16*   b2t   = (u16*)(ws + WS_B2T);
  u16*   tt    = (u16*)(ws + WS_TT);
  u16*   zt    = (u16*)(ws + WS_ZT);
  float* delta = (float*)(ws + WS_DELTA);
  u16*   db    = (u16*)(ws + OV_DB);
  u16*   Rbig  = (u16*)(ws + OV_RBIG);
  u16*   Ct    = (u16*)(ws + OV_CT);
  float* Hbuf  = (float*)(ws + OV_HBUF);
  u16*   S0    = (u16*)(ws + OV_SBUF);
  u16*   S1    = S0 + 256 * 1536;

  hipLaunchKernelGGL(k_zero,        dim3(1024),  dim3(256), 0, stream, delta);
  hipLaunchKernelGGL(k_repack_u,    dim3(6150),  dim3(256), 0, stream, u, ub);
  hipLaunchKernelGGL(k_repack_mphi, dim3(13824), dim3(256), 0, stream, mphi, ev, mphiT);
  hipLaunchKernelGGL(k_repack_mu,   dim3(6912),  dim3(256), 0, stream, mu, b2t);
  hipLaunchKernelGGL(k_make_T,      dim3(24576), dim3(256), 0, stream, evec, tt);
  hipLaunchKernelGGL(k_gemm_zt,     dim3(2304),  dim3(256), 0, stream, mphiT, ub + 2 * 768, zt);
  hipLaunchKernelGGL(k_gemm_delta,  dim3(816),   dim3(256), 0, stream, tt, zt, ub, b2t, delta);

  // --- scan prep in zt overlay (stream-ordered after k_gemm_delta) ---
  hipLaunchKernelGGL(k_buildR01, dim3(4608), dim3(256), 0, stream, my, Rbig, Rbig + RJ);
  hipLaunchKernelGGL(k_buildCt,  dim3(576),  dim3(256), 0, stream, Rbig + RJ, Rbig, Ct);
  hipLaunchKernelGGL(k_gemm_R,   dim3(72),   dim3(256), 0, stream, Rbig + RJ, Ct, Rbig + 2 * RJ);
  hipLaunchKernelGGL(k_buildCt,  dim3(576),  dim3(256), 0, stream, Rbig + 2 * RJ, Rbig + RJ, Ct);
  hipLaunchKernelGGL(k_gemm_R,   dim3(144),  dim3(256), 0, stream, Rbig + RJ, Ct, Rbig + 3 * RJ);
  hipLaunchKernelGGL(k_buildCt,  dim3(576),  dim3(256), 0, stream, Rbig + 4 * RJ, Rbig + 3 * RJ, Ct);
  hipLaunchKernelGGL(k_gemm_R,   dim3(288),  dim3(256), 0, stream, Rbig + RJ, Ct, Rbig + 5 * RJ);

  hipLaunchKernelGGL(k_repack_db, dim3(768),  dim3(256), 0, stream, delta, db);
  hipLaunchKernelGGL(k_zeroH,     dim3(1024), dim3(256), 0, stream, Hbuf);
  hipLaunchKernelGGL(k_conv,      dim3(384),  dim3(256), 0, stream, db, Rbig, Hbuf);

  // --- scan: init + 3 warm-up jumps + output ---
  hipLaunchKernelGGL(k_scan_init, dim3(1536), dim3(256), 0, stream, Hbuf, S0);
  hipLaunchKernelGGL(k_scan_round, dim3(24), dim3(256), 0, stream, S0, Rbig, Hbuf, S1, -17);
  hipLaunchKernelGGL(k_scan_round, dim3(24), dim3(256), 0, stream, S1, Rbig, Hbuf, S0, -9);
  hipLaunchKernelGGL(k_scan_round, dim3(24), dim3(256), 0, stream, S0, Rbig, Hbuf, S1, -1);
  hipLaunchKernelGGL(k_scan_out,  dim3(96),  dim3(256), 0, stream, S1, Rbig, Hbuf, out);
}

// Round 5
// 627.585 us; speedup vs baseline: 3.1124x; 1.0732x over previous
//
#include <hip/hip_runtime.h>
#include <hip/hip_bf16.h>
#include <stdint.h>

// STU forward: y = scan(m_y, (x_tilde @ m_phi) + AR(m_u, u))
// R5: 256x128 MFMA tiles for the two big GEMMs (32 MFMA per barrier-slab);
// launches fused 24 -> 11 (k_prep, k_chain_init, dual-write k_gemm_R, conv
// reads f32 delta, warm round A stages from Hbuf); 2 warm-up jumps.

typedef unsigned short u16;
typedef unsigned int   u32;
typedef __bf16  bf16x8 __attribute__((ext_vector_type(8)));
typedef float   f32x4  __attribute__((ext_vector_type(4)));
typedef u32     u32x4  __attribute__((ext_vector_type(4)));

#define MFMA(a,b,c) __builtin_amdgcn_mfma_f32_16x16x32_bf16(a,b,c,0,0,0)
#define RJ 1179648   // elems per R_j (768*1536)

__device__ __forceinline__ u16 f2b(float f) {           // fp32 -> bf16 bits, RNE
  union { float f; u32 u; } v; v.f = f;
  return (u16)((v.u + 0x7fffu + ((v.u >> 16) & 1u)) >> 16);
}

__device__ __forceinline__ void gld16(const u16* g, u16* l) {
  __builtin_amdgcn_global_load_lds(
      (const __attribute__((address_space(1))) u32*)g,
      (__attribute__((address_space(3))) u32*)l, 16, 0, 0);
}

// ---------------- workspace layout (bytes) ----------------
#define WS_UB     0            // [2050][768] bf16
#define WS_MPHIT  3148800      // [18432][768] bf16
#define WS_B2T    31460352     // [3][768][768] bf16
#define WS_TT     34999296     // [17][24][128][128] bf16 (slot 0 = delta-tile for dlt=-1, all zero)
#define WS_ZT     48368640     // [24][768][2048] bf16 (dead after k_gemm_delta)
#define WS_DELTA  123866112    // [2048][768] f32  (end 130157568)
// overlays inside zt region (phase 2, after k_gemm_delta):
#define OV_RBIG   (WS_ZT + 0)          // [9][768][1536] bf16
#define OV_CT0    (WS_ZT + 21233664)   // [1536][1536] bf16
#define OV_CT1    (WS_ZT + 25952256)
#define OV_CT2    (WS_ZT + 30670848)
#define OV_HBUF   (WS_ZT + 35389440)   // [2048][768] f32
#define OV_SBUF   (WS_ZT + 41680896)   // [2][256][1536] bf16

// ---------------------------------------------------------------------------
// k_prep: zero delta | repack u | repack mphi | repack mu | make_T  (one launch)
__global__ void k_prep(const float* __restrict__ u, const float* __restrict__ mphi,
                       const float* __restrict__ ev, const float* __restrict__ mu,
                       const float* __restrict__ evec,
                       float* __restrict__ delta, u16* __restrict__ ub,
                       u16* __restrict__ mphiT, u16* __restrict__ b2t,
                       u16* __restrict__ tt) {
  __shared__ float tile[32][33];
  int b = blockIdx.x, tid = threadIdx.x;
  if (b < 6144) {                       // zero delta
    delta[b * 256 + tid] = 0.f;
  } else if (b < 12294) {               // repack u (+2 guard rows)
    int i = (b - 6144) * 256 + tid;
    ub[i] = (i < 2 * 768) ? (u16)0 : f2b(u[i - 2 * 768]);
  } else if (b < 26118) {               // repack mphi (transpose per k, scale)
    int bid = b - 12294;
    int k = bid / 576, rem = bid % 576;
    int ti = rem / 24, tj = rem % 24;
    int c = tid & 31, r0 = tid >> 5;
    float s = powf(ev[k], 0.25f);
    #pragma unroll
    for (int rr = 0; rr < 4; ++rr) {
      int r = r0 + (rr << 3);
      tile[r][c] = mphi[(k * 768 + ti * 32 + r) * 768 + tj * 32 + c];
    }
    __syncthreads();
    #pragma unroll
    for (int rr = 0; rr < 4; ++rr) {
      int r = r0 + (rr << 3);
      mphiT[(k * 768 + tj * 32 + r) * 768 + ti * 32 + c] = f2b(tile[c][r] * s);
    }
  } else if (b < 33030) {               // repack mu
    int i = (b - 26118) * 256 + tid;
    int kk = i / (768 * 768);
    int rem = i % (768 * 768);
    int o = rem / 768, ii = rem % 768;
    b2t[i] = f2b(mu[(o * 768 + ii) * 3 + kk]);
  } else {                              // make_T (17 slots; slot 0 auto-zero)
    int i = (b - 33030) * 256 + tid;
    int c = i & 127, r = (i >> 7) & 127;
    int kk = (i >> 14) % 24, sl = (i >> 14) / 24;
    int t = (sl - 1) * 128 + r - c - 2;
    tt[i] = (t >= 0 && t < 2048) ? f2b(evec[t * 24 + kk]) : (u16)0;
  }
}

// ---------------------------------------------------------------------------
// Stage 128 rows x 64 u16 (16 KB) via async global_load_lds, XOR-swizzled:
// LDS slot (row, cb) holds global (row, cb ^ (row&7)).
__device__ __forceinline__ void stage128(const u16* __restrict__ g, int ld,
                                         u16* __restrict__ lds) {
  int tid = threadIdx.x;
  int r0 = tid >> 3, cb = tid & 7, wave = tid >> 6;
  #pragma unroll
  for (int s = 0; s < 4; ++s) {
    int row = r0 + (s << 5);
    int cbx = (cb ^ (row & 7)) << 3;
    gld16(g + row * ld + cbx, lds + (s << 11) + (wave << 9));
  }
}

// 128x128 tile MFMA over one K=64 slab (swizzle-aware reads).
__device__ __forceinline__ void mfma_tile(const u16* As, const u16* Bs, int lane,
                                          int wm, int wn, f32x4 acc[4][4]) {
  int cn = lane & 15, q = lane >> 4;
  #pragma unroll
  for (int ks = 0; ks < 2; ++ks) {
    int blk = ks * 4 + q;
    bf16x8 af[4], bg[4];
    #pragma unroll
    for (int i = 0; i < 4; ++i) {
      int row = wm + i * 16 + cn;
      af[i] = *(const bf16x8*)&As[row * 64 + ((blk ^ (row & 7)) << 3)];
    }
    #pragma unroll
    for (int j = 0; j < 4; ++j) {
      int row = wn + j * 16 + cn;
      bg[j] = *(const bf16x8*)&Bs[row * 64 + ((blk ^ (row & 7)) << 3)];
    }
    #pragma unroll
    for (int i = 0; i < 4; ++i)
      #pragma unroll
      for (int j = 0; j < 4; ++j)
        acc[i][j] = MFMA(af[i], bg[j], acc[i][j]);
  }
}

// 256x128 tile: wave owns 64 M-rows (wm = wave*64), all 128 N-cols. 32 MFMA/slab.
__device__ __forceinline__ void mfma_tile256(const u16* As, const u16* Bs, int lane,
                                             int wm, f32x4 acc[4][8]) {
  int cn = lane & 15, q = lane >> 4;
  #pragma unroll
  for (int ks = 0; ks < 2; ++ks) {
    int blk = ks * 4 + q;
    bf16x8 af[4], bg[8];
    #pragma unroll
    for (int i = 0; i < 4; ++i) {
      int row = wm + i * 16 + cn;
      af[i] = *(const bf16x8*)&As[row * 64 + ((blk ^ (row & 7)) << 3)];
    }
    #pragma unroll
    for (int j = 0; j < 8; ++j) {
      int row = j * 16 + cn;
      bg[j] = *(const bf16x8*)&Bs[row * 64 + ((blk ^ (row & 7)) << 3)];
    }
    #pragma unroll
    for (int i = 0; i < 4; ++i)
      #pragma unroll
      for (int j = 0; j < 8; ++j)
        acc[i][j] = MFMA(af[i], bg[j], acc[i][j]);
  }
}

// K2: Zt[18432 x 2048] = mphiT @ ub^T.  256x128 tiles, grid 72x16.
__global__ __launch_bounds__(256, 2) void k_gemm_zt(const u16* __restrict__ A,
                                                    const u16* __restrict__ B,
                                                    u16* __restrict__ C) {
  __shared__ __align__(16) u16 As[256 * 64];
  __shared__ __align__(16) u16 Bs[128 * 64];
  int bid = blockIdx.x;
  int nt = bid & 15, mt = bid >> 4;
  int m0 = mt << 8, n0 = nt << 7;
  int tid = threadIdx.x, lane = tid & 63, wave = tid >> 6;
  int wm = wave << 6;
  f32x4 acc[4][8] = {};
  for (int kb = 0; kb < 12; ++kb) {
    stage128(A + m0 * 768 + kb * 64, 768, As);
    stage128(A + (m0 + 128) * 768 + kb * 64, 768, As + 8192);
    stage128(B + n0 * 768 + kb * 64, 768, Bs);
    __syncthreads();
    mfma_tile256(As, Bs, lane, wm, acc);
    __syncthreads();
  }
  int q = lane >> 4, cn = lane & 15;
  #pragma unroll
  for (int i = 0; i < 4; ++i)
    #pragma unroll
    for (int j = 0; j < 8; ++j)
      #pragma unroll
      for (int r = 0; r < 4; ++r) {
        int m = m0 + wm + i * 16 + q * 4 + r;
        int n = n0 + j * 16 + cn;
        C[m * 2048 + n] = f2b(acc[i][j][r]);
      }
}

// K3: delta = sum_k T_k @ Zt[k] + AR.  256x128 tiles; block = (db, a, s).
// Rows 0-127 of the A tile use dlt = 2a-s (slot dlt+1; slot 0 is all-zero),
// rows 128-255 use dlt = 2a+1-s.
__global__ __launch_bounds__(256, 2) void k_gemm_delta(const u16* __restrict__ tt,
                                                       const u16* __restrict__ zt,
                                                       const u16* __restrict__ ub,
                                                       const u16* __restrict__ b2t,
                                                       float* __restrict__ delta) {
  __shared__ __align__(16) u16 As[256 * 64];
  __shared__ __align__(16) u16 Bs[128 * 64];
  int bid = blockIdx.x;
  int db = bid % 6;
  int r2 = bid / 6;                 // [0,72) -> (a, s), s in [0, 2a+2)
  int a = 0, s = 0;
  for (;; ++a) { int cnt = 2 * a + 2; if (r2 < cnt) { s = r2; break; } r2 -= cnt; }
  int n0 = db << 7;
  int tid = threadIdx.x, lane = tid & 63, wave = tid >> 6;
  int wm = wave << 6;
  f32x4 acc[4][8] = {};
  int d1 = 2 * a + 1 - s;                         // slot for lower half = d1+1
  const u16* A0 = tt + (size_t)d1 * 24 * 16384;         // slot d1 (= dlt0+1)
  const u16* A1 = tt + (size_t)(d1 + 1) * 24 * 16384;   // slot d1+1
  for (int kk = 0; kk < 24; ++kk) {
    const u16* Bg = zt + kk * (768 * 2048) + n0 * 2048 + s * 128;
    #pragma unroll
    for (int hf = 0; hf < 2; ++hf) {
      stage128(A0 + kk * 16384 + hf * 64, 128, As);
      stage128(A1 + kk * 16384 + hf * 64, 128, As + 8192);
      stage128(Bg + hf * 64, 2048, Bs);
      __syncthreads();
      mfma_tile256(As, Bs, lane, wm, acc);
      __syncthreads();
    }
  }
  // AR taps: tap kku owned by s == min(kku, 2a+1)
  #pragma unroll
  for (int kku = 0; kku < 3; ++kku) {
    int owner = (kku <= 2 * a + 1) ? kku : 2 * a + 1;
    if (s != owner) continue;
    const u16* Au = ub + (2 + a * 256 - kku) * 768;
    const u16* Bg = b2t + kku * (768 * 768) + n0 * 768;
    for (int ic = 0; ic < 12; ++ic) {
      stage128(Au + ic * 64, 768, As);
      stage128(Au + 128 * 768 + ic * 64, 768, As + 8192);
      stage128(Bg + ic * 64, 768, Bs);
      __syncthreads();
      mfma_tile256(As, Bs, lane, wm, acc);
      __syncthreads();
    }
  }
  int q = lane >> 4, cn = lane & 15;
  #pragma unroll
  for (int i = 0; i < 4; ++i)
    #pragma unroll
    for (int j = 0; j < 8; ++j)
      #pragma unroll
      for (int r = 0; r < 4; ++r) {
        int m = a * 256 + wm + i * 16 + q * 4 + r;
        int n = n0 + j * 16 + cn;
        unsafeAtomicAdd(&delta[m * 768 + n], acc[i][j][r]);
      }
}

// ---------------------------------------------------------------------------
// chain init: R_0=[I|0], R_1=[A1|A2], Ct0=[R_1;R_0]^T, Ct1 right half=R_1^T, zero H.
__global__ void k_chain_init(const float* __restrict__ my, u16* __restrict__ Rbig,
                             u16* __restrict__ Ct0, u16* __restrict__ Ct1,
                             float* __restrict__ Hbuf) {
  int b = blockIdx.x, tid = threadIdx.x;
  if (b < 4608) {                       // R_0, R_1
    int i = b * 256 + tid;
    int o = i / 1536, q = i % 1536;
    Rbig[i] = (q == o) ? (u16)0x3F80 : (u16)0;
    Rbig[RJ + i] = f2b(my[i]);
  } else if (b < 13824) {               // Ct0[n][p]
    int i = (b - 4608) * 256 + tid;
    int n = i / 1536, p = i % 1536;
    u16 v;
    if (p < 768) v = f2b(my[p * 1536 + n]);
    else         v = (p - 768 == n) ? (u16)0x3F80 : (u16)0;
    Ct0[i] = v;
  } else if (b < 18432) {               // Ct1[n][768+i] = R_1[i][n]
    int i = (b - 13824) * 256 + tid;
    int n = i / 768, ii = i % 768;
    Ct1[n * 1536 + 768 + ii] = f2b(my[ii * 1536 + n]);
  } else {                              // zero Hbuf
    int i = (b - 18432) * 256 + tid;
    Hbuf[i] = 0.f;
  }
}

// M x 1536 x 1536 GEMM (B = Ct, [n][k] layout). Dual epilogue: row-major out +
// optional transposed write into the next doubling's Ct.
// mode 0: none; 1: tcol=m (R_2^T -> left); 2: m<768 -> 768+m (R_3^T right),
// m>=768 -> m-768 (R_4^T left).
__global__ __launch_bounds__(256) void k_gemm_R(const u16* __restrict__ A,
                                                const u16* __restrict__ Ct,
                                                u16* __restrict__ Co,
                                                u16* __restrict__ CtT, int mode) {
  __shared__ __align__(16) u16 As[128 * 64];
  __shared__ __align__(16) u16 Bs[128 * 64];
  int bid = blockIdx.x;
  int nt = bid % 12, mt = bid / 12;
  int m0 = mt << 7, n0 = nt << 7;
  int tid = threadIdx.x, lane = tid & 63, wave = tid >> 6;
  int wm = (wave & 1) << 6, wn = (wave >> 1) << 6;
  f32x4 acc[4][4] = {};
  for (int kb = 0; kb < 24; ++kb) {
    stage128(A + m0 * 1536 + kb * 64, 1536, As);
    stage128(Ct + n0 * 1536 + kb * 64, 1536, Bs);
    __syncthreads();
    mfma_tile(As, Bs, lane, wm, wn, acc);
    __syncthreads();
  }
  int q = lane >> 4, cn = lane & 15;
  #pragma unroll
  for (int i = 0; i < 4; ++i)
    #pragma unroll
    for (int j = 0; j < 4; ++j) {
      int n = n0 + wn + j * 16 + cn;
      int mb = m0 + wm + i * 16 + q * 4;
      u16 pk[4];
      #pragma unroll
      for (int r = 0; r < 4; ++r) {
        u16 v = f2b(acc[i][j][r]);
        Co[(mb + r) * 1536 + n] = v;
        pk[r] = v;
      }
      if (mode) {
        int tcol = (mode == 1) ? mb : ((mb < 768) ? 768 + mb : mb - 768);
        *(uint2*)&CtT[n * 1536 + tcol] = *(uint2*)pk;
      }
    }
}

// H[t][o] = sum_{i<=t&7} U_i[o][:] . delta[t-i][:]  (delta read f32, cast on the fly)
__global__ __launch_bounds__(256) void k_conv(const float* __restrict__ delta,
                                              const u16* __restrict__ Rbig,
                                              float* __restrict__ Hbuf) {
  __shared__ __align__(16) u16 As[128 * 64];
  __shared__ __align__(16) u16 Bs[128 * 64];
  int bid = blockIdx.x;
  int nt = bid % 6, mt = (bid / 6) % 16, sp = bid / 96;
  int m0 = mt << 7, n0 = nt << 7;
  int tid = threadIdx.x, lane = tid & 63, wave = tid >> 6;
  int wm = (wave & 1) << 6, wn = (wave >> 1) << 6;
  int trow = tid >> 3, cb = tid & 7;
  f32x4 acc[4][4] = {};
  for (int kb = 0; kb < 24; ++kb) {
    int i = 2 * sp + kb / 12, dinb = kb % 12;
    #pragma unroll
    for (int s = 0; s < 4; ++s) {
      int row = trow + (s << 5);
      int t = m0 + row;
      u16 pk[8] = {0, 0, 0, 0, 0, 0, 0, 0};
      if (i <= (t & 7)) {
        const float* src = delta + (t - i) * 768 + dinb * 64 + (cb << 3);
        f32x4 v0 = *(const f32x4*)src;
        f32x4 v1 = *(const f32x4*)(src + 4);
        #pragma unroll
        for (int e = 0; e < 4; ++e) { pk[e] = f2b(v0[e]); pk[4 + e] = f2b(v1[e]); }
      }
      *(u32x4*)&As[row * 64 + ((cb ^ (row & 7)) << 3)] = *(u32x4*)pk;
    }
    stage128(Rbig + i * RJ + n0 * 1536 + dinb * 64, 1536, Bs);
    __syncthreads();
    mfma_tile(As, Bs, lane, wm, wn, acc);
    __syncthreads();
  }
  int q = lane >> 4, cn = lane & 15;
  #pragma unroll
  for (int i = 0; i < 4; ++i)
    #pragma unroll
    for (int j = 0; j < 4; ++j)
      #pragma unroll
      for (int r = 0; r < 4; ++r) {
        int m = m0 + wm + i * 16 + q * 4 + r;
        int n = n0 + wn + j * 16 + cn;
        unsafeAtomicAdd(&Hbuf[m * 768 + n], acc[i][j][r]);
      }
}

// warm round A: S[c] = J @ S0[c] + h(8c-9), where S0[c][q] = H[8c-17-(q>=768)][o]
// (A-operand staged from Hbuf on the fly).  J rows: n<768 -> R_8[n], else R_7[n-768].
__global__ __launch_bounds__(256) void k_scan_roundA(const u16* __restrict__ Rbig,
                                                     const float* __restrict__ Hbuf,
                                                     u16* __restrict__ Sout) {
  __shared__ __align__(16) u16 As[128 * 64];
  __shared__ __align__(16) u16 Bs[128 * 64];
  int bid = blockIdx.x;
  int nt = bid % 12, mt = bid / 12;
  int m0 = mt << 7, n0 = nt << 7;
  const u16* Bg = (nt < 6) ? (Rbig + 8 * RJ + n0 * 1536)
                           : (Rbig + 7 * RJ + (n0 - 768) * 1536);
  int tid = threadIdx.x, lane = tid & 63, wave = tid >> 6;
  int wm = (wave & 1) << 6, wn = (wave >> 1) << 6;
  int trow = tid >> 3, cb = tid & 7;
  f32x4 acc[4][4] = {};
  for (int kb = 0; kb < 24; ++kb) {
    #pragma unroll
    for (int s = 0; s < 4; ++s) {
      int row = trow + (s << 5);
      int c = m0 + row;
      int qb = kb * 64 + (cb << 3);
      int side = (qb >= 768) ? 1 : 0;
      int o0 = qb - side * 768;
      int t = 8 * c - 17 - side;
      u16 pk[8] = {0, 0, 0, 0, 0, 0, 0, 0};
      if (t >= 0) {
        const float* src = Hbuf + t * 768 + o0;
        f32x4 v0 = *(const f32x4*)src;
        f32x4 v1 = *(const f32x4*)(src + 4);
        #pragma unroll
        for (int e = 0; e < 4; ++e) { pk[e] = f2b(v0[e]); pk[4 + e] = f2b(v1[e]); }
      }
      *(u32x4*)&As[row * 64 + ((cb ^ (row & 7)) << 3)] = *(u32x4*)pk;
    }
    stage128(Bg + kb * 64, 1536, Bs);
    __syncthreads();
    mfma_tile(As, Bs, lane, wm, wn, acc);
    __syncthreads();
  }
  int q = lane >> 4, cn = lane & 15;
  #pragma unroll
  for (int i = 0; i < 4; ++i)
    #pragma unroll
    for (int j = 0; j < 4; ++j)
      #pragma unroll
      for (int r = 0; r < 4; ++r) {
        int c = m0 + wm + i * 16 + q * 4 + r;
        int n = n0 + wn + j * 16 + cn;
        int side = (n < 768) ? 0 : 1;
        int t = 8 * c - 9 - side;
        int o = n - side * 768;
        float val = acc[i][j][r] + ((t >= 0) ? Hbuf[t * 768 + o] : 0.f);
        Sout[c * 1536 + n] = f2b(val);
      }
}

// warm round B: Snew[c] = J @ Sin[c] + h(8c-1)
__global__ __launch_bounds__(256) void k_scan_round(const u16* __restrict__ Sin,
                                                    const u16* __restrict__ Rbig,
                                                    const float* __restrict__ Hbuf,
                                                    u16* __restrict__ Sout) {
  __shared__ __align__(16) u16 As[128 * 64];
  __shared__ __align__(16) u16 Bs[128 * 64];
  int bid = blockIdx.x;
  int nt = bid % 12, mt = bid / 12;
  int m0 = mt << 7, n0 = nt << 7;
  const u16* Bg = (nt < 6) ? (Rbig + 8 * RJ + n0 * 1536)
                           : (Rbig + 7 * RJ + (n0 - 768) * 1536);
  int tid = threadIdx.x, lane = tid & 63, wave = tid >> 6;
  int wm = (wave & 1) << 6, wn = (wave >> 1) << 6;
  f32x4 acc[4][4] = {};
  for (int kb = 0; kb < 24; ++kb) {
    stage128(Sin + m0 * 1536 + kb * 64, 1536, As);
    stage128(Bg + kb * 64, 1536, Bs);
    __syncthreads();
    mfma_tile(As, Bs, lane, wm, wn, acc);
    __syncthreads();
  }
  int q = lane >> 4, cn = lane & 15;
  #pragma unroll
  for (int i = 0; i < 4; ++i)
    #pragma unroll
    for (int j = 0; j < 4; ++j)
      #pragma unroll
      for (int r = 0; r < 4; ++r) {
        int c = m0 + wm + i * 16 + q * 4 + r;
        int n = n0 + wn + j * 16 + cn;
        int side = (n < 768) ? 0 : 1;
        int t = 8 * c - 1 - side;
        int o = n - side * 768;
        float val = acc[i][j][r] + ((t >= 0) ? Hbuf[t * 768 + o] : 0.f);
        Sout[c * 1536 + n] = f2b(val);
      }
}

// output: y[8c+jj] = (R_{jj+1} @ S[c])[o] + H[8c+jj][o]
__global__ __launch_bounds__(256) void k_scan_out(const u16* __restrict__ Sin,
                                                  const u16* __restrict__ Rbig,
                                                  const float* __restrict__ Hbuf,
                                                  float* __restrict__ out) {
  __shared__ __align__(16) u16 As[128 * 64];
  __shared__ __align__(16) u16 Bs[128 * 64];
  int bid = blockIdx.x;
  int nt = bid % 48, mt = bid / 48;
  int m0 = mt << 7, n0 = nt << 7;
  const u16* Bg = Rbig + RJ + n0 * 1536;   // rows of [R_1; ...; R_8]
  int tid = threadIdx.x, lane = tid & 63, wave = tid >> 6;
  int wm = (wave & 1) << 6, wn = (wave >> 1) << 6;
  f32x4 acc[4][4] = {};
  for (int kb = 0; kb < 24; ++kb) {
    stage128(Sin + m0 * 1536 + kb * 64, 1536, As);
    stage128(Bg + kb * 64, 1536, Bs);
    __syncthreads();
    mfma_tile(As, Bs, lane, wm, wn, acc);
    __syncthreads();
  }
  int q = lane >> 4, cn = lane & 15;
  #pragma unroll
  for (int i = 0; i < 4; ++i)
    #pragma unroll
    for (int j = 0; j < 4; ++j)
      #pragma unroll
      for (int r = 0; r < 4; ++r) {
        int c = m0 + wm + i * 16 + q * 4 + r;
        int n = n0 + wn + j * 16 + cn;
        int jj = n / 768, o = n % 768;
        int t = 8 * c + jj;
        out[t * 768 + o] = acc[i][j][r] + Hbuf[t * 768 + o];
      }
}

// ---------------------------------------------------------------------------
extern "C" void kernel_launch(void* const* d_in, const int* in_sizes, int n_in,
                              void* d_out, int out_size, void* d_ws, size_t ws_size,
                              hipStream_t stream) {
  const float* u    = (const float*)d_in[0];
  const float* my   = (const float*)d_in[1];
  const float* mu   = (const float*)d_in[2];
  const float* mphi = (const float*)d_in[3];
  const float* ev   = (const float*)d_in[4];
  const float* evec = (const float*)d_in[5];
  float* out = (float*)d_out;
  char* ws = (char*)d_ws;

  u16*   ub    = (u16*)(ws + WS_UB);
  u16*   mphiT = (u16*)(ws + WS_MPHIT);
  u16*   b2t   = (u16*)(ws + WS_B2T);
  u16*   tt    = (u16*)(ws + WS_TT);
  u16*   zt    = (u16*)(ws + WS_ZT);
  float* delta = (float*)(ws + WS_DELTA);
  u16*   Rbig  = (u16*)(ws + OV_RBIG);
  u16*   Ct0   = (u16*)(ws + OV_CT0);
  u16*   Ct1   = (u16*)(ws + OV_CT1);
  u16*   Ct2   = (u16*)(ws + OV_CT2);
  float* Hbuf  = (float*)(ws + OV_HBUF);
  u16*   SA    = (u16*)(ws + OV_SBUF);
  u16*   SB    = SA + 256 * 1536;

  hipLaunchKernelGGL(k_prep, dim3(59142), dim3(256), 0, stream,
                     u, mphi, ev, mu, evec, delta, ub, mphiT, b2t, tt);
  hipLaunchKernelGGL(k_gemm_zt,    dim3(1152), dim3(256), 0, stream,
                     mphiT, ub + 2 * 768, zt);
  hipLaunchKernelGGL(k_gemm_delta, dim3(432),  dim3(256), 0, stream,
                     tt, zt, ub, b2t, delta);

  // --- scan prep (overlays zt; stream-ordered after k_gemm_delta) ---
  hipLaunchKernelGGL(k_chain_init, dim3(24576), dim3(256), 0, stream,
                     my, Rbig, Ct0, Ct1, Hbuf);
  hipLaunchKernelGGL(k_gemm_R, dim3(72),  dim3(256), 0, stream,
                     Rbig + RJ, Ct0, Rbig + 2 * RJ, Ct1, 1);            // R_2
  hipLaunchKernelGGL(k_gemm_R, dim3(144), dim3(256), 0, stream,
                     Rbig + RJ, Ct1, Rbig + 3 * RJ, Ct2, 2);            // R_3,R_4
  hipLaunchKernelGGL(k_gemm_R, dim3(288), dim3(256), 0, stream,
                     Rbig + RJ, Ct2, Rbig + 5 * RJ, (u16*)nullptr, 0);  // R_5..R_8

  hipLaunchKernelGGL(k_conv, dim3(384), dim3(256), 0, stream, delta, Rbig, Hbuf);

  // --- scan: 2 warm-up jumps (A of round 1 staged from Hbuf) + output ---
  hipLaunchKernelGGL(k_scan_roundA, dim3(24), dim3(256), 0, stream, Rbig, Hbuf, SA);
  hipLaunchKernelGGL(k_scan_round,  dim3(24), dim3(256), 0, stream, SA, Rbig, Hbuf, SB);
  hipLaunchKernelGGL(k_scan_out,    dim3(96), dim3(256), 0, stream, SB, Rbig, Hbuf, out);
}